// Round 13
// baseline (123.968 us; speedup 1.0000x reference)
//
#include <hip/hip_runtime.h>
#include <cstdint>

// ---------------- problem constants ----------------
// QG=8, N=1024, DIM=512, H=8, D=64; rows/tensor=8192; HQ=64
// Gram fragment layout per hq ([4 blk16][32 kb][16 i15][4 q4][8] u16):
//   element (n, x) at blk(x>>4)*16384 + (n>>5)*512 + (x&15)*32 + ((n>>3)&3)*8 + (n&7)

typedef unsigned short u16;
typedef unsigned int u32;
typedef __attribute__((ext_vector_type(8))) unsigned short u16x8;
typedef __attribute__((ext_vector_type(4))) unsigned short u16x4;
typedef __attribute__((ext_vector_type(8))) short short8;
typedef __attribute__((ext_vector_type(4))) float floatx4;

// ---------------- workspace layout (float offsets) ----------------
#define WS_XBF     0LL          // bf16 [24576][512]  (q,k,v stacked, row-major)
#define WS_OATT    4194304LL    // bf16 [8192][512]   (aliases XBF tail)
#define WS_WPT     6291456LL    // bf16 W'T [512][512]
#define WS_WOT     6422528LL    // bf16 w_outT [512][512]
#define WS_U       6553600LL    // f32 [512]  g@W_in
#define WS_CB      6554112LL    // f32 [512]  b@W_in
#define WS_LNST    6554624LL    // f32 [24576][2] (mu, rsigma)
#define WS_FQ      6603776LL    // bf16 [64 hq][1024 n][64 d] row-major
#define WS_FKTS    8700928LL    // bf16 Gram frag per hq (K scaled by 1/|k|)
#define WS_FKTC    10798080LL   // bf16 Gram frag (K centered)
#define WS_FVT     12895232LL   // bf16 Gram frag (V)
#define WS_INVNQ   14992384LL   // f32 [64][1024]
#define WS_INVNK   15057920LL   // (written, unused downstream)
#define WS_QMEAN   15123456LL
#define WS_KMEAN   15188992LL   // (written, unused downstream)
#define WS_COLP    15254528LL   // f32 [2][64][8][64][2] (sum, sumsq)
#define WS_WGATE   15385600LL   // f32 [8] (+pad)
#define WS_WTF32   15385664LL   // f32 WT [512][512] (prep-phase only)
#define WS_GSUM    15385664LL   // f32 (gatered->gate only)
#define WS_MTB     15385664LL   // bf16 M^T [64 hq][64 d][64 e] (mc->apply)
#define WS_CTB     15516736LL   // bf16 C^T
#define WS_COLC    15647808LL   // f32 [64][64] colsum of C
// end = 15651904 floats = 62.6 MB

__device__ __forceinline__ float wsum(float v) {
#pragma unroll
    for (int m = 32; m; m >>= 1) v += __shfl_xor(v, m, 64);
    return v;
}
__device__ __forceinline__ u16 f2bf(float f) {
    u32 u = __float_as_uint(f);
    u32 r = u + 0x7fffu + ((u >> 16) & 1u);
    return (u16)(r >> 16);
}
__device__ __forceinline__ float bf2f(u16 u) {
    return __uint_as_float(((u32)u) << 16);
}

// ---------------- K0: LN row stats over DIM=512 + bf16 copy ----------------
__global__ __launch_bounds__(256) void k_lnstats(
    const float* __restrict__ q, const float* __restrict__ k,
    const float* __restrict__ v, float* __restrict__ ws) {
    int wid = threadIdx.x >> 6, lane = threadIdx.x & 63;
    int row = blockIdx.x * 4 + wid;            // 0..24575
    int t = row >> 13, r = row & 8191;
    const float* src = (t == 0) ? q : ((t == 1) ? k : v);
    const float4* p = (const float4*)(src + (size_t)r * 512) + lane * 2;
    float4 a = p[0], b = p[1];
    u16x8 o;
    o[0] = f2bf(a.x); o[1] = f2bf(a.y); o[2] = f2bf(a.z); o[3] = f2bf(a.w);
    o[4] = f2bf(b.x); o[5] = f2bf(b.y); o[6] = f2bf(b.z); o[7] = f2bf(b.w);
    *(u16x8*)((u16*)(ws + WS_XBF) + (size_t)row * 512 + lane * 8) = o;
    float s = a.x + a.y + a.z + a.w + b.x + b.y + b.z + b.w;
    float ss = a.x * a.x + a.y * a.y + a.z * a.z + a.w * a.w +
               b.x * b.x + b.y * b.y + b.z * b.z + b.w * b.w;
    s = wsum(s); ss = wsum(ss);
    if (lane == 0) {
        float mu = s * (1.f / 512.f);
        float var = ss * (1.f / 512.f) - mu * mu;
        ws[WS_LNST + (size_t)row * 2] = mu;
        ws[WS_LNST + (size_t)row * 2 + 1] = rsqrtf(var + 1e-5f);
    }
}

// ---------------- prep: transposed (scaled) bf16 weights (merged) ----------
// z=0: W=w_in, scaled by g, also writes WTF32;  z=1: W=w_out plain.
__global__ __launch_bounds__(256) void k_prep(
    const float* __restrict__ Wa, const float* __restrict__ Wb,
    const float* __restrict__ g, float* __restrict__ ws) {
    __shared__ float tile[64][65];
    int which = blockIdx.z;
    const float* W = which ? Wb : Wa;
    u16* Tb = (u16*)(ws + (which ? WS_WOT : WS_WPT));
    float* Tf = ws + WS_WTF32;
    int k0 = blockIdx.x * 64, j0 = blockIdx.y * 64;
    int tid = threadIdx.x;
    int c = (tid & 15) * 4, r0 = tid >> 4;
#pragma unroll
    for (int p = 0; p < 4; p++) {
        int r = r0 + p * 16;
        *(float4*)&tile[r][c] = *(const float4*)(W + (size_t)(k0 + r) * 512 + j0 + c);
    }
    __syncthreads();
    int kc = (tid & 15) * 4, jr0 = tid >> 4;
#pragma unroll
    for (int p = 0; p < 4; p++) {
        int jr = jr0 + p * 16;
        float v0 = tile[kc + 0][jr], v1 = tile[kc + 1][jr];
        float v2 = tile[kc + 2][jr], v3 = tile[kc + 3][jr];
        if (which == 0) {
            *(float4*)(Tf + (size_t)(j0 + jr) * 512 + k0 + kc) = (float4){v0, v1, v2, v3};
            v0 *= g[k0 + kc + 0]; v1 *= g[k0 + kc + 1];
            v2 *= g[k0 + kc + 2]; v3 *= g[k0 + kc + 3];
        }
        u16x4 ob = {f2bf(v0), f2bf(v1), f2bf(v2), f2bf(v3)};
        *(u16x4*)(Tb + (size_t)(j0 + jr) * 512 + k0 + kc) = ob;
    }
}

// ---------------- prep2: u = g@W, cb = b@W (from WT f32) ----------------
__global__ __launch_bounds__(256) void k_prep_u(
    const float* __restrict__ g, const float* __restrict__ b, float* __restrict__ ws) {
    int wid = threadIdx.x >> 6, lane = threadIdx.x & 63;
    int j = blockIdx.x * 4 + wid;              // 0..511
    const float* Tf = ws + WS_WTF32 + (size_t)j * 512;
    float su = 0.f, sc = 0.f;
#pragma unroll
    for (int m = 0; m < 8; m++) {
        int k = lane * 8 + m;
        float w = Tf[k];
        su += g[k] * w; sc += b[k] * w;
    }
    su = wsum(su); sc = wsum(sc);
    if (lane == 0) { ws[WS_U + j] = su; ws[WS_CB + j] = sc; }
}

// ------- K1 (proj): heterogeneous 512-block kernel, 2 blocks/CU ------------
// blocks 0..255: q+k fused (stage {Aq,Ak,B}, 16 MFMA/step);
// blocks 256..511: v only (stage {Av,B}, 8 MFMA/step).
// 3 bufs x 24KB = 72KB LDS, depth-2 prefetch, counted vmcnt (qk 3 ops/stage ->
// steady vmcnt(3); v 2 ops -> vmcnt(2)).  Epilogues = round-12 proven paths.
template <int CPX>
__global__ __launch_bounds__(512, 4) void k_proj(
    const u16* __restrict__ A, const u16* __restrict__ B, float* __restrict__ ws) {
    __shared__ char smem[73728];               // 3 bufs x 24KB
    int tid = threadIdx.x;
    int wid = tid >> 6, lane = tid & 63;
    int i15 = lane & 15, q4 = lane >> 4;
    int wm = wid >> 2, wn = wid & 3;
    int isv = (blockIdx.x >= 256);
    int flat = blockIdx.x - (isv ? 256 : 0);
    int swz = (flat & 7) * CPX + (flat >> 3);
    int c0 = (swz & 3) * 128, m0 = (swz >> 2) * 128;   // m0 in 0..8064

    const u16* gB = B + (size_t)c0 * 512;
    int o = wid * 1024 + lane * 16;            // byte off in 8KB region
    int srow = o >> 6, s8 = (o >> 4) & 3;
    int cch = (s8 - (srow >> 1)) & 3;          // inverse rotation
    size_t roffb = (size_t)srow * 512 + cch * 8;

    // epilogue shared helpers
    float2* rowred = (float2*)smem;            // [8 waves][64 rows]
    float2* colred = (float2*)(smem + 4096);   // [8 waves][32 cols]
    float2* lnfin  = (float2*)(smem + 6144);   // [2 hp][128 rows]
    int nbase = m0 & 1023;
    int qg = m0 >> 10, nblk = (m0 >> 7) & 7;
    int hp = wn >> 1;
    int h = (c0 >> 6) + hp, hq = h * 8 + qg;
    int dwn = (wn & 1) * 32;

    if (!isv) {
        // ---------------- q+k fused path ----------------
        floatx4 acc[2][4][2];
#pragma unroll
        for (int t = 0; t < 2; t++)
#pragma unroll
            for (int i = 0; i < 4; i++)
#pragma unroll
                for (int j = 0; j < 2; j++) acc[t][i][j] = (floatx4){0.f, 0.f, 0.f, 0.f};

        auto stage = [&](int ks, int buf) {
            size_t roff = roffb + ks * 32;
            char* base = smem + buf * 24576 + wid * 1024;
            __builtin_amdgcn_global_load_lds(
                (const __attribute__((address_space(1))) void*)(A + (size_t)m0 * 512 + roff),
                (__attribute__((address_space(3))) void*)(base), 16, 0, 0);
            __builtin_amdgcn_global_load_lds(
                (const __attribute__((address_space(1))) void*)(A + (size_t)(8192 + m0) * 512 + roff),
                (__attribute__((address_space(3))) void*)(base + 8192), 16, 0, 0);
            __builtin_amdgcn_global_load_lds(
                (const __attribute__((address_space(1))) void*)(gB + roff),
                (__attribute__((address_space(3))) void*)(base + 16384), 16, 0, 0);
        };

        stage(0, 0);
        stage(1, 1);
        __builtin_amdgcn_sched_barrier(0);
#pragma unroll
        for (int ks = 0; ks < 16; ks++) {
            __builtin_amdgcn_sched_barrier(0);
            if (ks <= 14) asm volatile("s_waitcnt vmcnt(3)" ::: "memory");
            else          asm volatile("s_waitcnt vmcnt(0)" ::: "memory");
            __builtin_amdgcn_s_barrier();
            __builtin_amdgcn_sched_barrier(0);
            if (ks + 2 < 16) stage(ks + 2, (ks + 2) % 3);
            __builtin_amdgcn_sched_barrier(0);
            char* bb = smem + (ks % 3) * 24576;
            short8 b[2];
#pragma unroll
            for (int f = 0; f < 2; f++) {
                int rb = wn * 32 + f * 16 + i15;
                int sb = (q4 + (rb >> 1)) & 3;
                b[f] = *(const short8*)(bb + 16384 + rb * 64 + sb * 16);
            }
#pragma unroll
            for (int t = 0; t < 2; t++) {
                short8 a[4];
#pragma unroll
                for (int f = 0; f < 4; f++) {
                    int ra = wm * 64 + f * 16 + i15;
                    int sa = (q4 + (ra >> 1)) & 3;
                    a[f] = *(const short8*)(bb + t * 8192 + ra * 64 + sa * 16);
                }
#pragma unroll
                for (int fm = 0; fm < 4; fm++)
#pragma unroll
                    for (int fn = 0; fn < 2; fn++)
                        acc[t][fm][fn] = __builtin_amdgcn_mfma_f32_16x16x32_bf16(
                            a[fm], b[fn], acc[t][fm][fn], 0, 0, 0);
            }
        }

        float u_[2], cb_[2];
#pragma unroll
        for (int fn = 0; fn < 2; fn++) {
            int gc = c0 + wn * 32 + fn * 16 + i15;
            u_[fn] = ws[WS_U + gc]; cb_[fn] = ws[WS_CB + gc];
        }
#pragma unroll
        for (int t = 0; t < 2; t++) {
            __syncthreads();
            float csum[2] = {0, 0}, css[2] = {0, 0};
#pragma unroll
            for (int fm = 0; fm < 4; fm++) {
#pragma unroll
                for (int reg = 0; reg < 4; reg++) {
                    int grow = t * 8192 + m0 + wm * 64 + fm * 16 + q4 * 4 + reg;
                    float2 st = *(const float2*)(ws + WS_LNST + (size_t)grow * 2);
                    float mu = st.x, rs = st.y;
                    float r1 = 0.f, r2 = 0.f;
#pragma unroll
                    for (int fn = 0; fn < 2; fn++) {
                        float val = rs * acc[t][fm][fn][reg] - rs * mu * u_[fn] + cb_[fn];
                        acc[t][fm][fn][reg] = val;
                        r1 += val; r2 += val * val;
                        csum[fn] += val; css[fn] += val * val;
                    }
#pragma unroll
                    for (int m = 1; m < 16; m <<= 1) {
                        r1 += __shfl_xor(r1, m, 64);
                        r2 += __shfl_xor(r2, m, 64);
                    }
                    if (i15 == fm * 4 + reg)
                        rowred[(size_t)wid * 64 + fm * 16 + q4 * 4 + reg] = (float2){r1, r2};
                }
            }
#pragma unroll
            for (int fn = 0; fn < 2; fn++) {
                float s1 = csum[fn], s2 = css[fn];
                s1 += __shfl_xor(s1, 16, 64); s1 += __shfl_xor(s1, 32, 64);
                s2 += __shfl_xor(s2, 16, 64); s2 += __shfl_xor(s2, 32, 64);
                if (q4 == fn) colred[(size_t)wid * 32 + fn * 16 + i15] = (float2){s1, s2};
            }
            __syncthreads();
            {
                float* invn = ws + (t ? WS_INVNK : WS_INVNQ);
                float* mean = ws + (t ? WS_KMEAN : WS_QMEAN);
                if (tid < 256) {               // 2 wm x 2 headpair x 64 rows
                    int wmf = tid >> 7, p = (tid >> 6) & 1, r = tid & 63;
                    float2 aa = rowred[(size_t)(wmf * 4 + 2 * p) * 64 + r];
                    float2 bb2 = rowred[(size_t)(wmf * 4 + 2 * p + 1) * 64 + r];
                    float s1 = aa.x + bb2.x, s2 = aa.y + bb2.y;
                    float iv = rsqrtf(s2), mn = s1 * (1.f / 64.f);
                    int n = nbase + wmf * 64 + r;
                    int hhq = ((c0 >> 6) + p) * 8 + qg;
                    invn[(size_t)hhq * 1024 + n] = iv;
                    mean[(size_t)hhq * 1024 + n] = mn;
                    lnfin[p * 128 + wmf * 64 + r] = (float2){iv, mn};
                } else if (tid < 384) {        // 2 headpair x 64 cols
                    int tt = tid - 256;
                    int p = tt >> 6, d = tt & 63;
                    int wnn = 2 * p + (d >> 5), loc = d & 31;
                    float2 aa = colred[(size_t)(0 * 4 + wnn) * 32 + loc];
                    float2 bb2 = colred[(size_t)(1 * 4 + wnn) * 32 + loc];
                    int hhq = ((c0 >> 6) + p) * 8 + qg;
                    *(float2*)(ws + WS_COLP +
                               (size_t)(((t * 64 + hhq) * 8 + nblk) * 64 + d) * 2) =
                        (float2){aa.x + bb2.x, aa.y + bb2.y};
                }
            }
            __syncthreads();
            if (t == 0) {                      // FQ row-major [hq][n][64]
                u16* fout = (u16*)(ws + WS_FQ) + (size_t)hq * 65536;
#pragma unroll
                for (int fm = 0; fm < 4; fm++)
#pragma unroll
                    for (int reg = 0; reg < 4; reg++) {
                        int n = nbase + wm * 64 + fm * 16 + q4 * 4 + reg;
#pragma unroll
                        for (int fn = 0; fn < 2; fn++)
                            fout[(size_t)n * 64 + dwn + fn * 16 + i15] =
                                f2bf(acc[0][fm][fn][reg]);
                    }
            } else {                           // FKTs/FKTc Gram frag
                u16* fs = (u16*)(ws + WS_FKTS) + (size_t)hq * 65536;
                u16* fc = (u16*)(ws + WS_FKTC) + (size_t)hq * 65536;
#pragma unroll
                for (int fn = 0; fn < 2; fn++) {
                    int eoff = ((wn & 1) * 2 + fn) * 16384 + i15 * 32;
#pragma unroll
                    for (int fm = 0; fm < 4; fm++) {
                        int n0l = wm * 64 + fm * 16 + q4 * 4;
                        int n0 = nbase + n0l;
                        int off = eoff + (n0 >> 5) * 512 + ((n0 >> 3) & 3) * 8 + (n0 & 7);
                        u16x4 vs, vc;
#pragma unroll
                        for (int reg = 0; reg < 4; reg++) {
                            float2 im = lnfin[hp * 128 + n0l + reg];
                            float val = acc[1][fm][fn][reg];
                            vs[reg] = f2bf(val * im.x);
                            vc[reg] = f2bf(val - im.y);
                        }
                        *(u16x4*)(fs + off) = vs;
                        *(u16x4*)(fc + off) = vc;
                    }
                }
            }
        }
    } else {
        // ---------------- v-only path ----------------
        floatx4 acc[4][2];
#pragma unroll
        for (int i = 0; i < 4; i++)
#pragma unroll
            for (int j = 0; j < 2; j++) acc[i][j] = (floatx4){0.f, 0.f, 0.f, 0.f};

        auto stage = [&](int ks, int buf) {
            size_t roff = roffb + ks * 32;
            char* base = smem + buf * 24576 + wid * 1024;
            __builtin_amdgcn_global_load_lds(
                (const __attribute__((address_space(1))) void*)(A + (size_t)(16384 + m0) * 512 + roff),
                (__attribute__((address_space(3))) void*)(base), 16, 0, 0);
            __builtin_amdgcn_global_load_lds(
                (const __attribute__((address_space(1))) void*)(gB + roff),
                (__attribute__((address_space(3))) void*)(base + 8192), 16, 0, 0);
        };

        stage(0, 0);
        stage(1, 1);
        __builtin_amdgcn_sched_barrier(0);
#pragma unroll
        for (int ks = 0; ks < 16; ks++) {
            __builtin_amdgcn_sched_barrier(0);
            if (ks <= 14) asm volatile("s_waitcnt vmcnt(2)" ::: "memory");
            else          asm volatile("s_waitcnt vmcnt(0)" ::: "memory");
            __builtin_amdgcn_s_barrier();
            __builtin_amdgcn_sched_barrier(0);
            if (ks + 2 < 16) stage(ks + 2, (ks + 2) % 3);
            __builtin_amdgcn_sched_barrier(0);
            char* bb = smem + (ks % 3) * 24576;
            short8 a[4], b[2];
#pragma unroll
            for (int f = 0; f < 4; f++) {
                int ra = wm * 64 + f * 16 + i15;
                int sa = (q4 + (ra >> 1)) & 3;
                a[f] = *(const short8*)(bb + ra * 64 + sa * 16);
            }
#pragma unroll
            for (int f = 0; f < 2; f++) {
                int rb = wn * 32 + f * 16 + i15;
                int sb = (q4 + (rb >> 1)) & 3;
                b[f] = *(const short8*)(bb + 8192 + rb * 64 + sb * 16);
            }
#pragma unroll
            for (int fm = 0; fm < 4; fm++)
#pragma unroll
                for (int fn = 0; fn < 2; fn++)
                    acc[fm][fn] = __builtin_amdgcn_mfma_f32_16x16x32_bf16(
                        a[fm], b[fn], acc[fm][fn], 0, 0, 0);
        }

        float u_[2], cb_[2];
#pragma unroll
        for (int fn = 0; fn < 2; fn++) {
            int gc = c0 + wn * 32 + fn * 16 + i15;
            u_[fn] = ws[WS_U + gc]; cb_[fn] = ws[WS_CB + gc];
        }
        u16* fv = (u16*)(ws + WS_FVT) + (size_t)hq * 65536;
#pragma unroll
        for (int fn = 0; fn < 2; fn++) {
            int doff = ((wn & 1) * 2 + fn) * 16384 + i15 * 32;
#pragma unroll
            for (int fm = 0; fm < 4; fm++) {
                int n0l = wm * 64 + fm * 16 + q4 * 4;
                int n0 = nbase + n0l;
                int off = doff + (n0 >> 5) * 512 + ((n0 >> 3) & 3) * 8 + (n0 & 7);
                u16x4 v4;
#pragma unroll
                for (int reg = 0; reg < 4; reg++) {
                    int grow = 16384 + m0 + n0l - (n0l) + wm * 64 + fm * 16 + q4 * 4 + reg;
                    // grow simplifies to 16384 + m0 + wm*64 + fm*16 + q4*4 + reg
                    float2 st = *(const float2*)(ws + WS_LNST + (size_t)grow * 2);
                    float val = st.y * acc[fm][fn][reg] - st.y * st.x * u_[fn] + cb_[fn];
                    v4[reg] = f2bf(val);
                }
                *(u16x4*)(fv + off) = v4;
            }
        }
    }
}

// ---------------- K6 (out-proj GEMM): round-10 proven structure ------------
template <int CPX>
__global__ __launch_bounds__(512, 4) void k_gemm_out(
    const u16* __restrict__ A, const u16* __restrict__ B,
    float* __restrict__ out, const float* __restrict__ bias) {
    __shared__ char smem[65536];               // 4 bufs x (A 8K + B 8K)
    int tid = threadIdx.x;
    int wid = tid >> 6, lane = tid & 63;
    int i15 = lane & 15, q4 = lane >> 4;
    int wm = wid >> 2, wn = wid & 3;
    int flat = blockIdx.x + (blockIdx.y << 2);
    int swz = (flat & 7) * CPX + (flat >> 3);
    int c0 = (swz & 3) * 128, m0 = (swz >> 2) * 128;

    floatx4 acc[4][2];
#pragma unroll
    for (int i = 0; i < 4; i++)
#pragma unroll
        for (int j = 0; j < 2; j++) acc[i][j] = (floatx4){0.f, 0.f, 0.f, 0.f};

    const u16* gA = A + (size_t)m0 * 512;
    const u16* gB = B + (size_t)c0 * 512;

    auto stage = [&](int ks, int buf) {
        int o = wid * 1024 + lane * 16;
        int srow = o >> 6, s = (o >> 4) & 3;
        int cch = (s - (srow >> 1)) & 3;
        const u16* ga = gA + (size_t)srow * 512 + ks * 32 + cch * 8;
        const u16* gb = gB + (size_t)srow * 512 + ks * 32 + cch * 8;
        char* la = smem + buf * 16384 + wid * 1024;
        char* lb = smem + buf * 16384 + 8192 + wid * 1024;
        __builtin_amdgcn_global_load_lds(
            (const __attribute__((address_space(1))) void*)ga,
            (__attribute__((address_space(3))) void*)la, 16, 0, 0);
        __builtin_amdgcn_global_load_lds(
            (const __attribute__((address_space(1))) void*)gb,
            (__attribute__((address_space(3))) void*)lb, 16, 0, 0);
    };

    stage(0, 0);
    stage(1, 1);
    stage(2, 2);
    __builtin_amdgcn_sched_barrier(0);
#pragma unroll
    for (int ks = 0; ks < 16; ks++) {
        __builtin_amdgcn_sched_barrier(0);
        if (ks <= 13)      asm volatile("s_waitcnt vmcnt(4)" ::: "memory");
        else if (ks == 14) asm volatile("s_waitcnt vmcnt(2)" ::: "memory");
        else               asm volatile("s_waitcnt vmcnt(0)" ::: "memory");
        __builtin_amdgcn_s_barrier();
        __builtin_amdgcn_sched_barrier(0);
        if (ks + 3 < 16) stage(ks + 3, (ks + 3) & 3);
        __builtin_amdgcn_sched_barrier(0);
        int buf = ks & 3;
        short8 a[4], b[2];
#pragma unroll
        for (int f = 0; f < 4; f++) {
            int ra = wm * 64 + f * 16 + i15;
            int sa = (q4 + (ra >> 1)) & 3;
            a[f] = *(const short8*)(smem + buf * 16384 + ra * 64 + sa * 16);
        }
#pragma unroll
        for (int f = 0; f < 2; f++) {
            int rb = wn * 32 + f * 16 + i15;
            int sb = (q4 + (rb >> 1)) & 3;
            b[f] = *(const short8*)(smem + buf * 16384 + 8192 + rb * 64 + sb * 16);
        }
#pragma unroll
        for (int fm = 0; fm < 4; fm++)
#pragma unroll
            for (int fn = 0; fn < 2; fn++)
                acc[fm][fn] = __builtin_amdgcn_mfma_f32_16x16x32_bf16(
                    a[fm], b[fn], acc[fm][fn], 0, 0, 0);
    }
#pragma unroll
    for (int fm = 0; fm < 4; fm++)
#pragma unroll
        for (int reg = 0; reg < 4; reg++) {
            int gm = m0 + wm * 64 + fm * 16 + q4 * 4 + reg;
#pragma unroll
            for (int fn = 0; fn < 2; fn++) {
                int gc = c0 + wn * 32 + fn * 16 + i15;
                out[(size_t)gm * 512 + gc] = acc[fm][fn][reg] + bias[gc];
            }
        }
}

// ---------------- K3a: parallel COLP reduction -> GSUM[2][8][64][2] --------
__global__ __launch_bounds__(256) void k_gatered(float* __restrict__ ws) {
    int h = blockIdx.x, t = blockIdx.y;
    int tid = threadIdx.x;
    int c = tid & 127, rg = tid >> 7;
    const float* base = ws + WS_COLP + ((size_t)(t * 64 + h * 8) * 8) * 128;
    float s = 0.f;
#pragma unroll 8
    for (int r = rg * 32; r < rg * 32 + 32; r++) s += base[(size_t)r * 128 + c];
    __shared__ float red[2][128];
    red[rg][c] = s;
    __syncthreads();
    if (tid < 128)
        ws[WS_GSUM + ((size_t)t * 8 + h) * 128 + tid] = red[0][tid] + red[1][tid];
}

// ---------------- K3b: gate MLP + variance penalty ----------------
__global__ __launch_bounds__(256) void k_gate(
    const float* __restrict__ pw1, const float* __restrict__ pb1,
    const float* __restrict__ plg, const float* __restrict__ plb,
    const float* __restrict__ pw2, const float* __restrict__ pb2,
    float* __restrict__ ws) {
    __shared__ float w1[128][64];
    __shared__ float gs[2][8][128];
    int tid = threadIdx.x, wid = tid >> 6, lane = tid & 63;
    for (int r = wid; r < 128; r += 4) w1[r][lane] = pw1[r * 64 + lane];
    for (int i = tid; i < 2048; i += 256) ((float*)gs)[i] = ws[WS_GSUM + i];
    __syncthreads();
    if (wid != 0) return;
    float Sq = 0, SSq = 0, Sk = 0, SSk = 0;
#pragma unroll
    for (int h = 0; h < 8; h++) {
        Sq += gs[0][h][lane * 2];  SSq += gs[0][h][lane * 2 + 1];
        Sk += gs[1][h][lane * 2];  SSk += gs[1][h][lane * 2 + 1];
    }
    const float NR = 65536.f;
    float stdq = sqrtf((SSq - Sq * Sq / NR) / (NR - 1.f) + 1e-4f);
    float stdk = sqrtf((SSk - Sk * Sk / NR) / (NR - 1.f) + 1e-4f);
    float vpen = (wsum(fmaxf(1.f - stdq, 0.f)) + wsum(fmaxf(1.f - stdk, 0.f))) * (1.f / 64.f);
    float gammav = plg[lane], betav = plb[lane], w2v = pw2[lane];
    for (int h = 0; h < 8; h++) {
        float y = pb1[lane];
#pragma unroll 8
        for (int i = 0; i < 64; i++) {
            y = fmaf(gs[0][h][i * 2] * (1.f / 8192.f), w1[i][lane], y);
            y = fmaf(gs[1][h][i * 2] * (1.f / 8192.f), w1[64 + i][lane], y);
        }
        float mu = wsum(y) * (1.f / 64.f);
        float dv = y - mu;
        float var = wsum(dv * dv) * (1.f / 64.f);
        float z = dv * rsqrtf(var + 1e-5f) * gammav + betav;
        float r = fmaxf(z, 0.f);
        float sdot = wsum(r * w2v);
        if (lane == 0) {
            float wv = 1.f / (1.f + expf(-(sdot + pb2[0])));
            ws[WS_WGATE + h] = wv / (1.f + vpen);
        }
    }
}

// ------- K4 (MFMA): M,C Gram matrices per hq, K=1024, barrier-free ---------
__global__ __launch_bounds__(256) void k_mc(float* __restrict__ ws) {
    int hq = blockIdx.x;
    int tid = threadIdx.x, wid = tid >> 6, lane = tid & 63;
    int i15 = lane & 15, q4 = lane >> 4;
    int we = wid >> 1, wd = wid & 1;
    const u16* fs = (const u16*)(ws + WS_FKTS) + (size_t)hq * 65536;
    const u16* fc = (const u16*)(ws + WS_FKTC) + (size_t)hq * 65536;
    const u16* fv = (const u16*)(ws + WS_FVT) + (size_t)hq * 65536;
    floatx4 aM[2][2], aC[2][2];
#pragma unroll
    for (int f = 0; f < 2; f++)
#pragma unroll
        for (int g = 0; g < 2; g++) {
            aM[f][g] = (floatx4){0.f, 0.f, 0.f, 0.f};
            aC[f][g] = (floatx4){0.f, 0.f, 0.f, 0.f};
        }
#pragma unroll 8
    for (int ks = 0; ks < 32; ks++) {
        short8 as_[2], ac_[2], b_[2];
#pragma unroll
        for (int f = 0; f < 2; f++) {
            int off = (we * 2 + f) * 16384 + ks * 512 + i15 * 32 + q4 * 8;
            as_[f] = *(const short8*)(fs + off);
            ac_[f] = *(const short8*)(fc + off);
        }
#pragma unroll
        for (int g = 0; g < 2; g++)
            b_[g] = *(const short8*)(fv + (wd * 2 + g) * 16384 + ks * 512 +
                                     i15 * 32 + q4 * 8);
#pragma unroll
        for (int f = 0; f < 2; f++)
#pragma unroll
            for (int g = 0; g < 2; g++) {
                aM[f][g] = __builtin_amdgcn_mfma_f32_16x16x32_bf16(
                    as_[f], b_[g], aM[f][g], 0, 0, 0);
                aC[f][g] = __builtin_amdgcn_mfma_f32_16x16x32_bf16(
                    ac_[f], b_[g], aC[f][g], 0, 0, 0);
            }
    }
    __shared__ float tile[2][64][65];
    __shared__ float cred[4][64];
#pragma unroll
    for (int f = 0; f < 2; f++)
#pragma unroll
        for (int g = 0; g < 2; g++)
#pragma unroll
            for (int reg = 0; reg < 4; reg++) {
                int e = we * 32 + f * 16 + q4 * 4 + reg;
                int d = wd * 32 + g * 16 + i15;
                tile[0][e][d] = aM[f][g][reg];
                tile[1][e][d] = aC[f][g][reg];
            }
    __syncthreads();
    int d = tid & 63, ec = tid >> 6;
    float cp = 0.f;
#pragma unroll
    for (int i = 0; i < 16; i++) cp += tile[1][ec * 16 + i][d];
    cred[ec][d] = cp;
#pragma unroll
    for (int mat = 0; mat < 2; mat++) {
        u16x8 p0, p1;
#pragma unroll
        for (int i = 0; i < 8; i++) {
            p0[i] = f2bf(tile[mat][ec * 16 + i][d]);
            p1[i] = f2bf(tile[mat][ec * 16 + 8 + i][d]);
        }
        u16* dst = (u16*)(ws + (mat ? WS_CTB : WS_MTB)) + (size_t)hq * 4096 + d * 64 + ec * 16;
        *(u16x8*)dst = p0;
        *(u16x8*)(dst + 8) = p1;
    }
    __syncthreads();
    if (tid < 64)
        ws[WS_COLC + (size_t)hq * 64 + tid] =
            cred[0][tid] + cred[1][tid] + cred[2][tid] + cred[3][tid];
}

// ---- K5 (MFMA): out_attn = c1*inv*(fq@M) + c2*(fq@C - qm*colC)  bf16 out ---
__global__ __launch_bounds__(256) void k_apply(float* __restrict__ ws) {
    int nt = blockIdx.x, hq = blockIdx.y;
    int h = hq >> 3, qg = hq & 7;
    __shared__ u16 mt[2][4096];                // swizzled M^T, C^T (8KB each)
    __shared__ float invqm[256][2];
    __shared__ u16 outs[256][66];              // +2 pad
    int tid = threadIdx.x, wid = tid >> 6, lane = tid & 63;
    int i15 = lane & 15, q4 = lane >> 4;
#pragma unroll
    for (int mat = 0; mat < 2; mat++) {
        const u16* src = (const u16*)(ws + (mat ? WS_CTB : WS_MTB)) + (size_t)hq * 4096;
#pragma unroll
        for (int it = 0; it < 2; it++) {
            int i = tid + it * 256;            // 16B chunk id, 512 total
            int d = i >> 3, c8 = i & 7;
            u16x8 v = *(const u16x8*)(src + i * 8);
            int byte = d * 128 + ((c8 * 16) ^ ((d & 7) << 4));
            *(u16x8*)((char*)&mt[mat][0] + byte) = v;
        }
    }
    int R0 = nt * 256;
    invqm[tid][0] = ws[WS_INVNQ + (size_t)hq * 1024 + R0 + tid];
    invqm[tid][1] = ws[WS_QMEAN + (size_t)hq * 1024 + R0 + tid];
    float wv = ws[WS_WGATE + h];
    float c1 = 1.f - wv, c2 = wv * (1.f / 64.f);
    float colc[4];
#pragma unroll
    for (int fn = 0; fn < 4; fn++)
        colc[fn] = ws[WS_COLC + (size_t)hq * 64 + fn * 16 + i15];
    __syncthreads();
    const u16* fq = (const u16*)(ws + WS_FQ) + (size_t)hq * 65536 +
                    (size_t)(R0 + wid * 64) * 64;
    floatx4 aM[4][4], aC[4][4];
#pragma unroll
    for (int i = 0; i < 4; i++)
#pragma unroll
        for (int j = 0; j < 4; j++) {
            aM[i][j] = (floatx4){0.f, 0.f, 0.f, 0.f};
            aC[i][j] = (floatx4){0.f, 0.f, 0.f, 0.f};
        }
#pragma unroll
    for (int ks = 0; ks < 2; ks++) {
        short8 a[4], bM[4], bC[4];
#pragma unroll
        for (int f = 0; f < 4; f++)
            a[f] = *(const short8*)(fq + (size_t)(f * 16 + i15) * 64 + q4 * 8 + ks * 32);
#pragma unroll
        for (int f = 0; f < 4; f++) {
            int col = f * 16 + i15;
            int byte = col * 128 + ((q4 * 16 + ks * 64) ^ ((col & 7) << 4));
            bM[f] = *(const short8*)((char*)&mt[0][0] + byte);
            bC[f] = *(const short8*)((char*)&mt[1][0] + byte);
        }
#pragma unroll
        for (int fm = 0; fm < 4; fm++)
#pragma unroll
            for (int fn = 0; fn < 4; fn++) {
                aM[fm][fn] = __builtin_amdgcn_mfma_f32_16x16x32_bf16(
                    a[fm], bM[fn], aM[fm][fn], 0, 0, 0);
                aC[fm][fn] = __builtin_amdgcn_mfma_f32_16x16x32_bf16(
                    a[fm], bC[fn], aC[fm][fn], 0, 0, 0);
            }
    }
#pragma unroll
    for (int fm = 0; fm < 4; fm++)
#pragma unroll
        for (int reg = 0; reg < 4; reg++) {
            int rloc = wid * 64 + fm * 16 + q4 * 4 + reg;
            float iv = invqm[rloc][0], qmv = invqm[rloc][1];
#pragma unroll
            for (int fn = 0; fn < 4; fn++) {
                float val = c1 * iv * aM[fm][fn][reg] +
                            c2 * (aC[fm][fn][reg] - qmv * colc[fn]);
                outs[rloc][fn * 16 + i15] = f2bf(val);
            }
        }
    __syncthreads();
    u16* oat = (u16*)(ws + WS_OATT);
#pragma unroll
    for (int it = 0; it < 8; it++) {
        int c = tid + it * 256;                // 16B chunk id, 2048 total
        int row = c >> 3, c8 = (c & 7) * 8;
        u16x8 v = *(const u16x8*)&outs[row][c8];
        *(u16x8*)(oat + ((size_t)qg * 1024 + R0 + row) * 512 + h * 64 + c8) = v;
    }
}

// ---------------- host launch ----------------
extern "C" void kernel_launch(void* const* d_in, const int* in_sizes, int n_in,
                              void* d_out, int out_size, void* d_ws, size_t ws_size,
                              hipStream_t stream) {
    (void)in_sizes; (void)n_in; (void)out_size; (void)ws_size;
    const float* q = (const float*)d_in[0];
    const float* k = (const float*)d_in[1];
    const float* v = (const float*)d_in[2];
    const float* ln_g = (const float*)d_in[3];
    const float* ln_b = (const float*)d_in[4];
    const float* w_in = (const float*)d_in[5];
    const float* p_w1 = (const float*)d_in[6];
    const float* p_b1 = (const float*)d_in[7];
    const float* p_ln_g = (const float*)d_in[8];
    const float* p_ln_b = (const float*)d_in[9];
    const float* p_w2 = (const float*)d_in[10];
    const float* p_b2 = (const float*)d_in[11];
    const float* w_out = (const float*)d_in[12];
    const float* b_out = (const float*)d_in[13];
    float* ws = (float*)d_ws;
    float* out = (float*)d_out;

    k_lnstats<<<6144, 256, 0, stream>>>(q, k, v, ws);
    k_prep<<<dim3(8, 8, 2), 256, 0, stream>>>(w_in, w_out, ln_g, ws);
    k_prep_u<<<128, 256, 0, stream>>>(ln_g, ln_b, ws);
    k_proj<32><<<512, 512, 0, stream>>>((const u16*)(ws + WS_XBF),
                                        (const u16*)(ws + WS_WPT), ws);
    k_gatered<<<dim3(8, 2), 256, 0, stream>>>(ws);
    k_gate<<<1, 256, 0, stream>>>(p_w1, p_b1, p_ln_g, p_ln_b, p_w2, p_b2, ws);
    k_mc<<<64, 256, 0, stream>>>(ws);
    k_apply<<<dim3(4, 64), 256, 0, stream>>>(ws);
    k_gemm_out<32><<<dim3(4, 64), 512, 0, stream>>>((const u16*)(ws + WS_OATT),
                                                    (const u16*)(ws + WS_WOT), out, b_out);
}

// Round 14
// 109.861 us; speedup vs baseline: 1.1284x; 1.1284x over previous
//
#include <hip/hip_runtime.h>
#include <cstdint>

// ---------------- problem constants ----------------
// QG=8, N=1024, DIM=512, H=8, D=64; rows/tensor=8192; HQ=64
// Gram fragment layout per hq ([4 blk16][32 kb][16 i15][4 q4][8] u16):
//   element (n, x) at blk(x>>4)*16384 + (n>>5)*512 + (x&15)*32 + ((n>>3)&3)*8 + (n&7)

typedef unsigned short u16;
typedef unsigned int u32;
typedef __attribute__((ext_vector_type(8))) unsigned short u16x8;
typedef __attribute__((ext_vector_type(4))) unsigned short u16x4;
typedef __attribute__((ext_vector_type(8))) short short8;
typedef __attribute__((ext_vector_type(4))) float floatx4;

// ---------------- workspace layout (float offsets) ----------------
#define WS_XBF     0LL          // bf16 [24576][512]  (q,k,v stacked, row-major)
#define WS_OATT    4194304LL    // bf16 [8192][512]   (aliases XBF tail)
#define WS_WPT     6291456LL    // bf16 W'T [512][512]
#define WS_WOT     6422528LL    // bf16 w_outT [512][512]
#define WS_U       6553600LL    // (unused; kept for layout stability)
#define WS_CB      6554112LL
#define WS_LNST    6554624LL    // f32 [24576][2] (mu, rsigma)
#define WS_FQ      6603776LL    // bf16 [64 hq][1024 n][64 d] row-major
#define WS_FKTS    8700928LL    // bf16 Gram frag per hq (K scaled by 1/|k|)
#define WS_FKTC    10798080LL   // bf16 Gram frag (K centered)
#define WS_FVT     12895232LL   // bf16 Gram frag (V)
#define WS_INVNQ   14992384LL   // f32 [64][1024]
#define WS_INVNK   15057920LL   // (written, unused downstream)
#define WS_QMEAN   15123456LL
#define WS_KMEAN   15188992LL   // (written, unused downstream)
#define WS_COLP    15254528LL   // f32 [2][64][8][64][2] (sum, sumsq)
#define WS_WGATE   15385600LL   // f32 [8] (+pad)
#define WS_UP      15385664LL   // f32 [8][512] u partials (prep->proj)
#define WS_CBP     15389760LL   // f32 [8][512] cb partials
#define WS_GSUM    15393856LL   // f32 [2][8][64][2] (gatered->gate only)
#define WS_MTB     15395904LL   // bf16 M^T [64 hq][64 d][64 e] (mc->apply)
#define WS_CTB     15526976LL   // bf16 C^T
#define WS_COLC    15658048LL   // f32 [64][64] colsum of C
// end = 15662144 floats = 62.6 MB

__device__ __forceinline__ float wsum(float v) {
#pragma unroll
    for (int m = 32; m; m >>= 1) v += __shfl_xor(v, m, 64);
    return v;
}
__device__ __forceinline__ u16 f2bf(float f) {
    u32 u = __float_as_uint(f);
    u32 r = u + 0x7fffu + ((u >> 16) & 1u);
    return (u16)(r >> 16);
}
__device__ __forceinline__ float bf2f(u16 u) {
    return __uint_as_float(((u32)u) << 16);
}

// ---- K0 (merged): blocks 0..6143 = LN stats + bf16 copy;
//      blocks 6144..6271 = weight transpose prep (+ u/cb partials for w_in) ----
__global__ __launch_bounds__(256) void k_head(
    const float* __restrict__ q, const float* __restrict__ k,
    const float* __restrict__ v, const float* __restrict__ w_in,
    const float* __restrict__ w_out, const float* __restrict__ g,
    const float* __restrict__ b, float* __restrict__ ws) {
    __shared__ float tile[64][65];
    int bid = blockIdx.x;
    int tid = threadIdx.x;
    if (bid < 6144) {
        int wid = tid >> 6, lane = tid & 63;
        int row = bid * 4 + wid;               // 0..24575
        int t = row >> 13, r = row & 8191;
        const float* src = (t == 0) ? q : ((t == 1) ? k : v);
        const float4* p = (const float4*)(src + (size_t)r * 512) + lane * 2;
        float4 a = p[0], bb = p[1];
        u16x8 o;
        o[0] = f2bf(a.x); o[1] = f2bf(a.y); o[2] = f2bf(a.z); o[3] = f2bf(a.w);
        o[4] = f2bf(bb.x); o[5] = f2bf(bb.y); o[6] = f2bf(bb.z); o[7] = f2bf(bb.w);
        *(u16x8*)((u16*)(ws + WS_XBF) + (size_t)row * 512 + lane * 8) = o;
        float s = a.x + a.y + a.z + a.w + bb.x + bb.y + bb.z + bb.w;
        float ss = a.x * a.x + a.y * a.y + a.z * a.z + a.w * a.w +
                   bb.x * bb.x + bb.y * bb.y + bb.z * bb.z + bb.w * bb.w;
        s = wsum(s); ss = wsum(ss);
        if (lane == 0) {
            float mu = s * (1.f / 512.f);
            float var = ss * (1.f / 512.f) - mu * mu;
            ws[WS_LNST + (size_t)row * 2] = mu;
            ws[WS_LNST + (size_t)row * 2 + 1] = rsqrtf(var + 1e-5f);
        }
    } else {
        int pb = bid - 6144;                   // 0..127
        int which = pb >> 6;                   // 0: w_in (scaled), 1: w_out
        int rem = pb & 63;
        int k0 = (rem >> 3) * 64, j0 = (rem & 7) * 64;
        const float* W = which ? w_out : w_in;
        u16* Tb = (u16*)(ws + (which ? WS_WOT : WS_WPT));
        int c = (tid & 15) * 4, r0 = tid >> 4;
#pragma unroll
        for (int p = 0; p < 4; p++) {
            int r = r0 + p * 16;
            *(float4*)&tile[r][c] = *(const float4*)(W + (size_t)(k0 + r) * 512 + j0 + c);
        }
        __syncthreads();
        int kc = (tid & 15) * 4, jr0 = tid >> 4;
#pragma unroll
        for (int p = 0; p < 4; p++) {
            int jr = jr0 + p * 16;
            float v0 = tile[kc + 0][jr], v1 = tile[kc + 1][jr];
            float v2 = tile[kc + 2][jr], v3 = tile[kc + 3][jr];
            if (which == 0) {
                v0 *= g[k0 + kc + 0]; v1 *= g[k0 + kc + 1];
                v2 *= g[k0 + kc + 2]; v3 *= g[k0 + kc + 3];
            }
            u16x4 ob = {f2bf(v0), f2bf(v1), f2bf(v2), f2bf(v3)};
            *(u16x4*)(Tb + (size_t)(j0 + jr) * 512 + k0 + kc) = ob;
        }
        if (which == 0) {                      // u/cb partials over this k-block
            int jl = tid & 63, qt = tid >> 6;
            float su = 0.f, sc = 0.f;
#pragma unroll
            for (int r = 0; r < 16; r++) {
                int kk = qt * 16 + r;
                float w = tile[kk][jl];
                su += g[k0 + kk] * w; sc += b[k0 + kk] * w;
            }
            __syncthreads();
            float* red = &tile[0][0];
            red[qt * 128 + jl] = su;
            red[qt * 128 + 64 + jl] = sc;
            __syncthreads();
            if (tid < 64) {
                float s = red[tid] + red[128 + tid] + red[256 + tid] + red[384 + tid];
                ws[WS_UP + (size_t)(k0 >> 6) * 512 + j0 + tid] = s;
            } else if (tid < 128) {
                int j = tid - 64;
                float s = red[64 + j] + red[192 + j] + red[320 + j] + red[448 + j];
                ws[WS_CBP + (size_t)(k0 >> 6) * 512 + j0 + j] = s;
            }
        }
    }
}

// ------- K1 (proj, q/k/v fused): 3x A-tiles share one B panel --------------
// Round-12 proven structure: 4 bufs x 32KB = 128KB LDS, depth-3 prefetch,
// vmcnt(8) steady, grid (4,64) = 1 block/CU, 24 MFMA/step.
template <int CPX>
__global__ __launch_bounds__(512, 2) void k_proj(
    const u16* __restrict__ A, const u16* __restrict__ B, float* __restrict__ ws) {
    __shared__ char smem[131072];              // 4 bufs x {Aq,Ak,Av,B}x8KB
    int tid = threadIdx.x;
    int wid = tid >> 6, lane = tid & 63;
    int i15 = lane & 15, q4 = lane >> 4;
    int wm = wid >> 2, wn = wid & 3;
    int flat = blockIdx.x + (blockIdx.y << 2);
    int swz = (flat & 7) * CPX + (flat >> 3);
    int c0 = (swz & 3) * 128, m0 = (swz >> 2) * 128;   // m0 in 0..8064

    floatx4 acc[3][4][2];
#pragma unroll
    for (int t = 0; t < 3; t++)
#pragma unroll
        for (int i = 0; i < 4; i++)
#pragma unroll
            for (int j = 0; j < 2; j++) acc[t][i][j] = (floatx4){0.f, 0.f, 0.f, 0.f};

    const u16* gB = B + (size_t)c0 * 512;

    auto stage = [&](int ks, int buf) {
        int o = wid * 1024 + lane * 16;        // byte off in 8KB region
        int srow = o >> 6, s = (o >> 4) & 3;
        int cch = (s - (srow >> 1)) & 3;       // inverse rotation
        size_t roff = (size_t)srow * 512 + ks * 32 + cch * 8;
        char* base = smem + buf * 32768 + wid * 1024;
#pragma unroll
        for (int t = 0; t < 3; t++) {
            const u16* ga = A + (size_t)(t * 8192 + m0) * 512 + roff;
            __builtin_amdgcn_global_load_lds(
                (const __attribute__((address_space(1))) void*)ga,
                (__attribute__((address_space(3))) void*)(base + t * 8192), 16, 0, 0);
        }
        __builtin_amdgcn_global_load_lds(
            (const __attribute__((address_space(1))) void*)(gB + roff),
            (__attribute__((address_space(3))) void*)(base + 24576), 16, 0, 0);
    };

    stage(0, 0);
    stage(1, 1);
    stage(2, 2);
    __builtin_amdgcn_sched_barrier(0);
#pragma unroll
    for (int ks = 0; ks < 16; ks++) {
        __builtin_amdgcn_sched_barrier(0);
        if (ks <= 13)      asm volatile("s_waitcnt vmcnt(8)" ::: "memory");
        else if (ks == 14) asm volatile("s_waitcnt vmcnt(4)" ::: "memory");
        else               asm volatile("s_waitcnt vmcnt(0)" ::: "memory");
        __builtin_amdgcn_s_barrier();
        __builtin_amdgcn_sched_barrier(0);
        if (ks + 3 < 16) stage(ks + 3, (ks + 3) & 3);   // post-barrier: safe
        __builtin_amdgcn_sched_barrier(0);
        char* bb = smem + (ks & 3) * 32768;
        short8 b[2];
#pragma unroll
        for (int f = 0; f < 2; f++) {
            int rb = wn * 32 + f * 16 + i15;
            int sb = (q4 + (rb >> 1)) & 3;     // rotation swizzle
            b[f] = *(const short8*)(bb + 24576 + rb * 64 + sb * 16);
        }
#pragma unroll
        for (int t = 0; t < 3; t++) {
            short8 a[4];
#pragma unroll
            for (int f = 0; f < 4; f++) {
                int ra = wm * 64 + f * 16 + i15;
                int sa = (q4 + (ra >> 1)) & 3;
                a[f] = *(const short8*)(bb + t * 8192 + ra * 64 + sa * 16);
            }
#pragma unroll
            for (int fm = 0; fm < 4; fm++)
#pragma unroll
                for (int fn = 0; fn < 2; fn++)
                    acc[t][fm][fn] = __builtin_amdgcn_mfma_f32_16x16x32_bf16(
                        a[fm], b[fn], acc[t][fm][fn], 0, 0, 0);
        }
    }

    // ---------------- epilogue: per-t LN fold + stats + writes ----------
    float2* rowred = (float2*)smem;            // [8 waves][64 rows]
    float2* colred = (float2*)(smem + 4096);   // [8 waves][32 cols]
    float2* lnfin  = (float2*)(smem + 6144);   // [2 hp][128 rows] (inv,mean)
    int nbase = m0 & 1023;                     // per-hq row base
    int qg = m0 >> 10, nblk = (m0 >> 7) & 7;
    int hp = wn >> 1;
    int h = (c0 >> 6) + hp, hq = h * 8 + qg;
    int dwn = (wn & 1) * 32;
    float u_[2], cb_[2];
#pragma unroll
    for (int fn = 0; fn < 2; fn++) {
        int gc = c0 + wn * 32 + fn * 16 + i15;
        float su = 0.f, sc = 0.f;
#pragma unroll
        for (int p = 0; p < 8; p++) {
            su += ws[WS_UP + (size_t)p * 512 + gc];
            sc += ws[WS_CBP + (size_t)p * 512 + gc];
        }
        u_[fn] = su; cb_[fn] = sc;
    }
#pragma unroll
    for (int t = 0; t < 3; t++) {
        __syncthreads();                       // scratch free (K-loop / prev t)
        float csum[2] = {0, 0}, css[2] = {0, 0};
#pragma unroll
        for (int fm = 0; fm < 4; fm++) {
#pragma unroll
            for (int reg = 0; reg < 4; reg++) {
                int grow = t * 8192 + m0 + wm * 64 + fm * 16 + q4 * 4 + reg;  // LNST row
                float2 st = *(const float2*)(ws + WS_LNST + (size_t)grow * 2);
                float mu = st.x, rs = st.y;
                float r1 = 0.f, r2 = 0.f;
#pragma unroll
                for (int fn = 0; fn < 2; fn++) {
                    float val = rs * acc[t][fm][fn][reg] - rs * mu * u_[fn] + cb_[fn];
                    acc[t][fm][fn][reg] = val;
                    r1 += val; r2 += val * val;
                    csum[fn] += val; css[fn] += val * val;
                }
                if (t < 2) {
#pragma unroll
                    for (int m = 1; m < 16; m <<= 1) {
                        r1 += __shfl_xor(r1, m, 64);
                        r2 += __shfl_xor(r2, m, 64);
                    }
                    if (i15 == fm * 4 + reg)
                        rowred[(size_t)wid * 64 + fm * 16 + q4 * 4 + reg] = (float2){r1, r2};
                }
            }
        }
        if (t < 2) {
#pragma unroll
            for (int fn = 0; fn < 2; fn++) {
                float s1 = csum[fn], s2 = css[fn];
                s1 += __shfl_xor(s1, 16, 64); s1 += __shfl_xor(s1, 32, 64);
                s2 += __shfl_xor(s2, 16, 64); s2 += __shfl_xor(s2, 32, 64);
                if (q4 == fn) colred[(size_t)wid * 32 + fn * 16 + i15] = (float2){s1, s2};
            }
        }
        __syncthreads();
        if (t < 2) {
            float* invn = ws + (t ? WS_INVNK : WS_INVNQ);
            float* mean = ws + (t ? WS_KMEAN : WS_QMEAN);
            if (tid < 256) {                   // 2 wm x 2 headpair x 64 rows
                int wmf = tid >> 7, p = (tid >> 6) & 1, r = tid & 63;
                float2 aa = rowred[(size_t)(wmf * 4 + 2 * p) * 64 + r];
                float2 bb2 = rowred[(size_t)(wmf * 4 + 2 * p + 1) * 64 + r];
                float s1 = aa.x + bb2.x, s2 = aa.y + bb2.y;
                float iv = rsqrtf(s2), mn = s1 * (1.f / 64.f);
                int n = nbase + wmf * 64 + r;
                int hhq = ((c0 >> 6) + p) * 8 + qg;
                invn[(size_t)hhq * 1024 + n] = iv;
                mean[(size_t)hhq * 1024 + n] = mn;
                lnfin[p * 128 + wmf * 64 + r] = (float2){iv, mn};
            } else if (tid < 384) {            // 2 headpair x 64 cols
                int tt = tid - 256;
                int p = tt >> 6, d = tt & 63;
                int wnn = 2 * p + (d >> 5), loc = d & 31;
                float2 aa = colred[(size_t)(0 * 4 + wnn) * 32 + loc];
                float2 bb2 = colred[(size_t)(1 * 4 + wnn) * 32 + loc];
                int hhq = ((c0 >> 6) + p) * 8 + qg;
                *(float2*)(ws + WS_COLP +
                           (size_t)(((t * 64 + hhq) * 8 + nblk) * 64 + d) * 2) =
                    (float2){aa.x + bb2.x, aa.y + bb2.y};
            }
        }
        __syncthreads();
        if (t == 0) {                          // FQ row-major [hq][n][64]
            u16* fout = (u16*)(ws + WS_FQ) + (size_t)hq * 65536;
#pragma unroll
            for (int fm = 0; fm < 4; fm++)
#pragma unroll
                for (int reg = 0; reg < 4; reg++) {
                    int n = nbase + wm * 64 + fm * 16 + q4 * 4 + reg;
#pragma unroll
                    for (int fn = 0; fn < 2; fn++)
                        fout[(size_t)n * 64 + dwn + fn * 16 + i15] =
                            f2bf(acc[0][fm][fn][reg]);
                }
        } else if (t == 1) {                   // FKTs/FKTc Gram frag
            u16* fs = (u16*)(ws + WS_FKTS) + (size_t)hq * 65536;
            u16* fc = (u16*)(ws + WS_FKTC) + (size_t)hq * 65536;
#pragma unroll
            for (int fn = 0; fn < 2; fn++) {
                int eoff = ((wn & 1) * 2 + fn) * 16384 + i15 * 32;
#pragma unroll
                for (int fm = 0; fm < 4; fm++) {
                    int n0l = wm * 64 + fm * 16 + q4 * 4;
                    int n0 = nbase + n0l;
                    int off = eoff + (n0 >> 5) * 512 + ((n0 >> 3) & 3) * 8 + (n0 & 7);
                    u16x4 vs, vc;
#pragma unroll
                    for (int reg = 0; reg < 4; reg++) {
                        float2 im = lnfin[hp * 128 + n0l + reg];
                        float val = acc[1][fm][fn][reg];
                        vs[reg] = f2bf(val * im.x);
                        vc[reg] = f2bf(val - im.y);
                    }
                    *(u16x4*)(fs + off) = vs;
                    *(u16x4*)(fc + off) = vc;
                }
            }
        } else {                               // FVT Gram frag
            u16* fv = (u16*)(ws + WS_FVT) + (size_t)hq * 65536;
#pragma unroll
            for (int fn = 0; fn < 2; fn++) {
                int doff = ((wn & 1) * 2 + fn) * 16384 + i15 * 32;
#pragma unroll
                for (int fm = 0; fm < 4; fm++) {
                    int n0 = nbase + wm * 64 + fm * 16 + q4 * 4;
                    int off = doff + (n0 >> 5) * 512 + ((n0 >> 3) & 3) * 8 + (n0 & 7);
                    u16x4 v4;
#pragma unroll
                    for (int reg = 0; reg < 4; reg++) v4[reg] = f2bf(acc[2][fm][fn][reg]);
                    *(u16x4*)(fv + off) = v4;
                }
            }
        }
    }
}

// ---------------- K6 (out-proj GEMM): round-10 proven structure ------------
template <int CPX>
__global__ __launch_bounds__(512, 4) void k_gemm_out(
    const u16* __restrict__ A, const u16* __restrict__ B,
    float* __restrict__ out, const float* __restrict__ bias) {
    __shared__ char smem[65536];               // 4 bufs x (A 8K + B 8K)
    int tid = threadIdx.x;
    int wid = tid >> 6, lane = tid & 63;
    int i15 = lane & 15, q4 = lane >> 4;
    int wm = wid >> 2, wn = wid & 3;
    int flat = blockIdx.x + (blockIdx.y << 2);
    int swz = (flat & 7) * CPX + (flat >> 3);
    int c0 = (swz & 3) * 128, m0 = (swz >> 2) * 128;

    floatx4 acc[4][2];
#pragma unroll
    for (int i = 0; i < 4; i++)
#pragma unroll
        for (int j = 0; j < 2; j++) acc[i][j] = (floatx4){0.f, 0.f, 0.f, 0.f};

    const u16* gA = A + (size_t)m0 * 512;
    const u16* gB = B + (size_t)c0 * 512;

    auto stage = [&](int ks, int buf) {
        int o = wid * 1024 + lane * 16;
        int srow = o >> 6, s = (o >> 4) & 3;
        int cch = (s - (srow >> 1)) & 3;
        const u16* ga = gA + (size_t)srow * 512 + ks * 32 + cch * 8;
        const u16* gb = gB + (size_t)srow * 512 + ks * 32 + cch * 8;
        char* la = smem + buf * 16384 + wid * 1024;
        char* lb = smem + buf * 16384 + 8192 + wid * 1024;
        __builtin_amdgcn_global_load_lds(
            (const __attribute__((address_space(1))) void*)ga,
            (__attribute__((address_space(3))) void*)la, 16, 0, 0);
        __builtin_amdgcn_global_load_lds(
            (const __attribute__((address_space(1))) void*)gb,
            (__attribute__((address_space(3))) void*)lb, 16, 0, 0);
    };

    stage(0, 0);
    stage(1, 1);
    stage(2, 2);
    __builtin_amdgcn_sched_barrier(0);
#pragma unroll
    for (int ks = 0; ks < 16; ks++) {
        __builtin_amdgcn_sched_barrier(0);
        if (ks <= 13)      asm volatile("s_waitcnt vmcnt(4)" ::: "memory");
        else if (ks == 14) asm volatile("s_waitcnt vmcnt(2)" ::: "memory");
        else               asm volatile("s_waitcnt vmcnt(0)" ::: "memory");
        __builtin_amdgcn_s_barrier();
        __builtin_amdgcn_sched_barrier(0);
        if (ks + 3 < 16) stage(ks + 3, (ks + 3) & 3);
        __builtin_amdgcn_sched_barrier(0);
        int buf = ks & 3;
        short8 a[4], b[2];
#pragma unroll
        for (int f = 0; f < 4; f++) {
            int ra = wm * 64 + f * 16 + i15;
            int sa = (q4 + (ra >> 1)) & 3;
            a[f] = *(const short8*)(smem + buf * 16384 + ra * 64 + sa * 16);
        }
#pragma unroll
        for (int f = 0; f < 2; f++) {
            int rb = wn * 32 + f * 16 + i15;
            int sb = (q4 + (rb >> 1)) & 3;
            b[f] = *(const short8*)(smem + buf * 16384 + 8192 + rb * 64 + sb * 16);
        }
#pragma unroll
        for (int fm = 0; fm < 4; fm++)
#pragma unroll
            for (int fn = 0; fn < 2; fn++)
                acc[fm][fn] = __builtin_amdgcn_mfma_f32_16x16x32_bf16(
                    a[fm], b[fn], acc[fm][fn], 0, 0, 0);
    }
#pragma unroll
    for (int fm = 0; fm < 4; fm++)
#pragma unroll
        for (int reg = 0; reg < 4; reg++) {
            int gm = m0 + wm * 64 + fm * 16 + q4 * 4 + reg;
#pragma unroll
            for (int fn = 0; fn < 2; fn++) {
                int gc = c0 + wn * 32 + fn * 16 + i15;
                out[(size_t)gm * 512 + gc] = acc[fm][fn][reg] + bias[gc];
            }
        }
}

// ---------------- K3a: parallel COLP reduction -> GSUM[2][8][64][2] --------
__global__ __launch_bounds__(256) void k_gatered(float* __restrict__ ws) {
    int h = blockIdx.x, t = blockIdx.y;
    int tid = threadIdx.x;
    int c = tid & 127, rg = tid >> 7;
    const float* base = ws + WS_COLP + ((size_t)(t * 64 + h * 8) * 8) * 128;
    float s = 0.f;
#pragma unroll 8
    for (int r = rg * 32; r < rg * 32 + 32; r++) s += base[(size_t)r * 128 + c];
    __shared__ float red[2][128];
    red[rg][c] = s;
    __syncthreads();
    if (tid < 128)
        ws[WS_GSUM + ((size_t)t * 8 + h) * 128 + tid] = red[0][tid] + red[1][tid];
}

// ---------------- K3b: gate MLP + variance penalty ----------------
__global__ __launch_bounds__(256) void k_gate(
    const float* __restrict__ pw1, const float* __restrict__ pb1,
    const float* __restrict__ plg, const float* __restrict__ plb,
    const float* __restrict__ pw2, const float* __restrict__ pb2,
    float* __restrict__ ws) {
    __shared__ float w1[128][64];
    __shared__ float gs[2][8][128];
    int tid = threadIdx.x, wid = tid >> 6, lane = tid & 63;
    for (int r = wid; r < 128; r += 4) w1[r][lane] = pw1[r * 64 + lane];
    for (int i = tid; i < 2048; i += 256) ((float*)gs)[i] = ws[WS_GSUM + i];
    __syncthreads();
    if (wid != 0) return;
    float Sq = 0, SSq = 0, Sk = 0, SSk = 0;
#pragma unroll
    for (int h = 0; h < 8; h++) {
        Sq += gs[0][h][lane * 2];  SSq += gs[0][h][lane * 2 + 1];
        Sk += gs[1][h][lane * 2];  SSk += gs[1][h][lane * 2 + 1];
    }
    const float NR = 65536.f;
    float stdq = sqrtf((SSq - Sq * Sq / NR) / (NR - 1.f) + 1e-4f);
    float stdk = sqrtf((SSk - Sk * Sk / NR) / (NR - 1.f) + 1e-4f);
    float vpen = (wsum(fmaxf(1.f - stdq, 0.f)) + wsum(fmaxf(1.f - stdk, 0.f))) * (1.f / 64.f);
    float gammav = plg[lane], betav = plb[lane], w2v = pw2[lane];
    for (int h = 0; h < 8; h++) {
        float y = pb1[lane];
#pragma unroll 8
        for (int i = 0; i < 64; i++) {
            y = fmaf(gs[0][h][i * 2] * (1.f / 8192.f), w1[i][lane], y);
            y = fmaf(gs[1][h][i * 2] * (1.f / 8192.f), w1[64 + i][lane], y);
        }
        float mu = wsum(y) * (1.f / 64.f);
        float dv = y - mu;
        float var = wsum(dv * dv) * (1.f / 64.f);
        float z = dv * rsqrtf(var + 1e-5f) * gammav + betav;
        float r = fmaxf(z, 0.f);
        float sdot = wsum(r * w2v);
        if (lane == 0) {
            float wv = 1.f / (1.f + expf(-(sdot + pb2[0])));
            ws[WS_WGATE + h] = wv / (1.f + vpen);
        }
    }
}

// ------- K4 (MFMA): M,C Gram matrices per hq, K=1024, barrier-free ---------
__global__ __launch_bounds__(256) void k_mc(float* __restrict__ ws) {
    int hq = blockIdx.x;
    int tid = threadIdx.x, wid = tid >> 6, lane = tid & 63;
    int i15 = lane & 15, q4 = lane >> 4;
    int we = wid >> 1, wd = wid & 1;
    const u16* fs = (const u16*)(ws + WS_FKTS) + (size_t)hq * 65536;
    const u16* fc = (const u16*)(ws + WS_FKTC) + (size_t)hq * 65536;
    const u16* fv = (const u16*)(ws + WS_FVT) + (size_t)hq * 65536;
    floatx4 aM[2][2], aC[2][2];
#pragma unroll
    for (int f = 0; f < 2; f++)
#pragma unroll
        for (int g = 0; g < 2; g++) {
            aM[f][g] = (floatx4){0.f, 0.f, 0.f, 0.f};
            aC[f][g] = (floatx4){0.f, 0.f, 0.f, 0.f};
        }
#pragma unroll 8
    for (int ks = 0; ks < 32; ks++) {
        short8 as_[2], ac_[2], b_[2];
#pragma unroll
        for (int f = 0; f < 2; f++) {
            int off = (we * 2 + f) * 16384 + ks * 512 + i15 * 32 + q4 * 8;
            as_[f] = *(const short8*)(fs + off);
            ac_[f] = *(const short8*)(fc + off);
        }
#pragma unroll
        for (int g = 0; g < 2; g++)
            b_[g] = *(const short8*)(fv + (wd * 2 + g) * 16384 + ks * 512 +
                                     i15 * 32 + q4 * 8);
#pragma unroll
        for (int f = 0; f < 2; f++)
#pragma unroll
            for (int g = 0; g < 2; g++) {
                aM[f][g] = __builtin_amdgcn_mfma_f32_16x16x32_bf16(
                    as_[f], b_[g], aM[f][g], 0, 0, 0);
                aC[f][g] = __builtin_amdgcn_mfma_f32_16x16x32_bf16(
                    ac_[f], b_[g], aC[f][g], 0, 0, 0);
            }
    }
    __shared__ float tile[2][64][65];
    __shared__ float cred[4][64];
#pragma unroll
    for (int f = 0; f < 2; f++)
#pragma unroll
        for (int g = 0; g < 2; g++)
#pragma unroll
            for (int reg = 0; reg < 4; reg++) {
                int e = we * 32 + f * 16 + q4 * 4 + reg;
                int d = wd * 32 + g * 16 + i15;
                tile[0][e][d] = aM[f][g][reg];
                tile[1][e][d] = aC[f][g][reg];
            }
    __syncthreads();
    int d = tid & 63, ec = tid >> 6;
    float cp = 0.f;
#pragma unroll
    for (int i = 0; i < 16; i++) cp += tile[1][ec * 16 + i][d];
    cred[ec][d] = cp;
#pragma unroll
    for (int mat = 0; mat < 2; mat++) {
        u16x8 p0, p1;
#pragma unroll
        for (int i = 0; i < 8; i++) {
            p0[i] = f2bf(tile[mat][ec * 16 + i][d]);
            p1[i] = f2bf(tile[mat][ec * 16 + 8 + i][d]);
        }
        u16* dst = (u16*)(ws + (mat ? WS_CTB : WS_MTB)) + (size_t)hq * 4096 + d * 64 + ec * 16;
        *(u16x8*)dst = p0;
        *(u16x8*)(dst + 8) = p1;
    }
    __syncthreads();
    if (tid < 64)
        ws[WS_COLC + (size_t)hq * 64 + tid] =
            cred[0][tid] + cred[1][tid] + cred[2][tid] + cred[3][tid];
}

// ---- K5 (MFMA): out_attn = c1*inv*(fq@M) + c2*(fq@C - qm*colC)  bf16 out ---
__global__ __launch_bounds__(256) void k_apply(float* __restrict__ ws) {
    int nt = blockIdx.x, hq = blockIdx.y;
    int h = hq >> 3, qg = hq & 7;
    __shared__ u16 mt[2][4096];                // swizzled M^T, C^T (8KB each)
    __shared__ float invqm[256][2];
    __shared__ u16 outs[256][66];              // +2 pad
    int tid = threadIdx.x, wid = tid >> 6, lane = tid & 63;
    int i15 = lane & 15, q4 = lane >> 4;
#pragma unroll
    for (int mat = 0; mat < 2; mat++) {
        const u16* src = (const u16*)(ws + (mat ? WS_CTB : WS_MTB)) + (size_t)hq * 4096;
#pragma unroll
        for (int it = 0; it < 2; it++) {
            int i = tid + it * 256;            // 16B chunk id, 512 total
            int d = i >> 3, c8 = i & 7;
            u16x8 v = *(const u16x8*)(src + i * 8);
            int byte = d * 128 + ((c8 * 16) ^ ((d & 7) << 4));
            *(u16x8*)((char*)&mt[mat][0] + byte) = v;
        }
    }
    int R0 = nt * 256;
    invqm[tid][0] = ws[WS_INVNQ + (size_t)hq * 1024 + R0 + tid];
    invqm[tid][1] = ws[WS_QMEAN + (size_t)hq * 1024 + R0 + tid];
    float wv = ws[WS_WGATE + h];
    float c1 = 1.f - wv, c2 = wv * (1.f / 64.f);
    float colc[4];
#pragma unroll
    for (int fn = 0; fn < 4; fn++)
        colc[fn] = ws[WS_COLC + (size_t)hq * 64 + fn * 16 + i15];
    __syncthreads();
    const u16* fq = (const u16*)(ws + WS_FQ) + (size_t)hq * 65536 +
                    (size_t)(R0 + wid * 64) * 64;
    floatx4 aM[4][4], aC[4][4];
#pragma unroll
    for (int i = 0; i < 4; i++)
#pragma unroll
        for (int j = 0; j < 4; j++) {
            aM[i][j] = (floatx4){0.f, 0.f, 0.f, 0.f};
            aC[i][j] = (floatx4){0.f, 0.f, 0.f, 0.f};
        }
#pragma unroll
    for (int ks = 0; ks < 2; ks++) {
        short8 a[4], bM[4], bC[4];
#pragma unroll
        for (int f = 0; f < 4; f++)
            a[f] = *(const short8*)(fq + (size_t)(f * 16 + i15) * 64 + q4 * 8 + ks * 32);
#pragma unroll
        for (int f = 0; f < 4; f++) {
            int col = f * 16 + i15;
            int byte = col * 128 + ((q4 * 16 + ks * 64) ^ ((col & 7) << 4));
            bM[f] = *(const short8*)((char*)&mt[0][0] + byte);
            bC[f] = *(const short8*)((char*)&mt[1][0] + byte);
        }
#pragma unroll
        for (int fm = 0; fm < 4; fm++)
#pragma unroll
            for (int fn = 0; fn < 4; fn++) {
                aM[fm][fn] = __builtin_amdgcn_mfma_f32_16x16x32_bf16(
                    a[fm], bM[fn], aM[fm][fn], 0, 0, 0);
                aC[fm][fn] = __builtin_amdgcn_mfma_f32_16x16x32_bf16(
                    a[fm], bC[fn], aC[fm][fn], 0, 0, 0);
            }
    }
#pragma unroll
    for (int fm = 0; fm < 4; fm++)
#pragma unroll
        for (int reg = 0; reg < 4; reg++) {
            int rloc = wid * 64 + fm * 16 + q4 * 4 + reg;
            float iv = invqm[rloc][0], qmv = invqm[rloc][1];
#pragma unroll
            for (int fn = 0; fn < 4; fn++) {
                float val = c1 * iv * aM[fm][fn][reg] +
                            c2 * (aC[fm][fn][reg] - qmv * colc[fn]);
                outs[rloc][fn * 16 + i15] = f2bf(val);
            }
        }
    __syncthreads();
    u16* oat = (u16*)(ws + WS_OATT);
#pragma unroll
    for (int it = 0; it < 8; it++) {
        int c = tid + it * 256;                // 16B chunk id, 2048 total
        int row = c >> 3, c8 = (c & 7) * 8;
        u16x8 v = *(const u16x8*)&outs[row][c8];
        *(u16x8*)(oat + ((size_t)qg * 1024 + R0 + row) * 512 + h * 64 + c8) = v;
    }
}

// ---------------- host launch ----------------
extern "C" void kernel_launch(void* const* d_in, const int* in_sizes, int n_in,
                              void* d_out, int out_size, void* d_ws, size_t ws_size,
                              hipStream_t stream) {
    (void)in_sizes; (void)n_in; (void)out_size; (void)ws_size;
    const float* q = (const float*)d_in[0];
    const float* k = (const float*)d_in[1];
    const float* v = (const float*)d_in[2];
    const float* ln_g = (const float*)d_in[3];
    const float* ln_b = (const float*)d_in[4];
    const float* w_in = (const float*)d_in[5];
    const float* p_w1 = (const float*)d_in[6];
    const float* p_b1 = (const float*)d_in[7];
    const float* p_ln_g = (const float*)d_in[8];
    const float* p_ln_b = (const float*)d_in[9];
    const float* p_w2 = (const float*)d_in[10];
    const float* p_b2 = (const float*)d_in[11];
    const float* w_out = (const float*)d_in[12];
    const float* b_out = (const float*)d_in[13];
    float* ws = (float*)d_ws;
    float* out = (float*)d_out;

    k_head<<<6272, 256, 0, stream>>>(q, k, v, w_in, w_out, ln_g, ln_b, ws);
    k_proj<32><<<dim3(4, 64), 512, 0, stream>>>((const u16*)(ws + WS_XBF),
                                                (const u16*)(ws + WS_WPT), ws);
    k_gatered<<<dim3(8, 2), 256, 0, stream>>>(ws);
    k_gate<<<1, 256, 0, stream>>>(p_w1, p_b1, p_ln_g, p_ln_b, p_w2, p_b2, ws);
    k_mc<<<64, 256, 0, stream>>>(ws);
    k_apply<<<dim3(4, 64), 256, 0, stream>>>(ws);
    k_gemm_out<32><<<dim3(4, 64), 512, 0, stream>>>((const u16*)(ws + WS_OATT),
                                                    (const u16*)(ws + WS_WOT), out, b_out);
}

// Round 16
// 94.074 us; speedup vs baseline: 1.3178x; 1.1678x over previous
//
#include <hip/hip_runtime.h>
#include <cstdint>

// ---------------- problem constants ----------------
// QG=8, N=1024, DIM=512, H=8, D=64; rows/tensor=8192; HQ=64
// Gram fragment layout per hq ([4 blk16][32 kb][16 i15][4 q4][8] u16):
//   element (n, x) at blk(x>>4)*16384 + (n>>5)*512 + (x&15)*32 + ((n>>3)&3)*8 + (n&7)

typedef unsigned short u16;
typedef unsigned int u32;
typedef __attribute__((ext_vector_type(8))) unsigned short u16x8;
typedef __attribute__((ext_vector_type(4))) unsigned short u16x4;
typedef __attribute__((ext_vector_type(8))) short short8;
typedef __attribute__((ext_vector_type(4))) float floatx4;

// ---------------- workspace layout (float offsets) ----------------
#define WS_XBF     0LL          // bf16 [24576][512]  (q,k,v stacked, row-major)
#define WS_OATT    4194304LL    // bf16 [8192][512]   (aliases XBF tail)
#define WS_WPT     6291456LL    // bf16 W'T [512][512]
#define WS_WOT     6422528LL    // bf16 w_outT [512][512]
#define WS_LNST    6554624LL    // f32 [24576][2] (mu, rsigma)
#define WS_FQ      6603776LL    // bf16 [64 hq][1024 n][64 d] row-major
#define WS_FKTS    8700928LL    // bf16 Gram frag per hq (K scaled by 1/|k|)
#define WS_FKTC    10798080LL   // bf16 Gram frag (K centered)
#define WS_FVT     12895232LL   // bf16 Gram frag (V)
#define WS_INVNQ   14992384LL   // f32 [64][1024]
#define WS_INVNK   15057920LL   // (written, unused downstream)
#define WS_QMEAN   15123456LL
#define WS_KMEAN   15188992LL   // (written, unused downstream)
#define WS_COLP    15254528LL   // f32 [2][64][8][64][2] (sum, sumsq)
#define WS_WGATE   15385600LL   // f32 [8] (+pad)
#define WS_UP      15385664LL   // f32 [8][512] u partials (prep->proj)
#define WS_CBP     15389760LL   // f32 [8][512] cb partials
#define WS_GSUM    15393856LL   // f32 [2][8][64][2] (gatered->mc gate)
#define WS_MTB     15395904LL   // bf16 M^T [64 hq][64 d][64 e] (mc->apply)
#define WS_CTB     15526976LL   // bf16 C^T
#define WS_COLC    15658048LL   // f32 [64][64] colsum of C
// end = 15662144 floats = 62.6 MB

__device__ __forceinline__ float wsum(float v) {
#pragma unroll
    for (int m = 32; m; m >>= 1) v += __shfl_xor(v, m, 64);
    return v;
}
__device__ __forceinline__ u16 f2bf(float f) {
    u32 u = __float_as_uint(f);
    u32 r = u + 0x7fffu + ((u >> 16) & 1u);
    return (u16)(r >> 16);
}
__device__ __forceinline__ float bf2f(u16 u) {
    return __uint_as_float(((u32)u) << 16);
}

// ---- K0 (merged): blocks 0..6143 = LN stats + bf16 copy;
//      blocks 6144..6271 = weight transpose prep (+ u/cb partials for w_in) ----
__global__ __launch_bounds__(256) void k_head(
    const float* __restrict__ q, const float* __restrict__ k,
    const float* __restrict__ v, const float* __restrict__ w_in,
    const float* __restrict__ w_out, const float* __restrict__ g,
    const float* __restrict__ b, float* __restrict__ ws) {
    __shared__ float tile[64][65];
    int bid = blockIdx.x;
    int tid = threadIdx.x;
    if (bid < 6144) {
        int wid = tid >> 6, lane = tid & 63;
        int row = bid * 4 + wid;               // 0..24575
        int t = row >> 13, r = row & 8191;
        const float* src = (t == 0) ? q : ((t == 1) ? k : v);
        const float4* p = (const float4*)(src + (size_t)r * 512) + lane * 2;
        float4 a = p[0], bb = p[1];
        u16x8 o;
        o[0] = f2bf(a.x); o[1] = f2bf(a.y); o[2] = f2bf(a.z); o[3] = f2bf(a.w);
        o[4] = f2bf(bb.x); o[5] = f2bf(bb.y); o[6] = f2bf(bb.z); o[7] = f2bf(bb.w);
        *(u16x8*)((u16*)(ws + WS_XBF) + (size_t)row * 512 + lane * 8) = o;
        float s = a.x + a.y + a.z + a.w + bb.x + bb.y + bb.z + bb.w;
        float ss = a.x * a.x + a.y * a.y + a.z * a.z + a.w * a.w +
                   bb.x * bb.x + bb.y * bb.y + bb.z * bb.z + bb.w * bb.w;
        s = wsum(s); ss = wsum(ss);
        if (lane == 0) {
            float mu = s * (1.f / 512.f);
            float var = ss * (1.f / 512.f) - mu * mu;
            ws[WS_LNST + (size_t)row * 2] = mu;
            ws[WS_LNST + (size_t)row * 2 + 1] = rsqrtf(var + 1e-5f);
        }
    } else {
        int pb = bid - 6144;                   // 0..127
        int which = pb >> 6;                   // 0: w_in (scaled), 1: w_out
        int rem = pb & 63;
        int k0 = (rem >> 3) * 64, j0 = (rem & 7) * 64;
        const float* W = which ? w_out : w_in;
        u16* Tb = (u16*)(ws + (which ? WS_WOT : WS_WPT));
        int c = (tid & 15) * 4, r0 = tid >> 4;
#pragma unroll
        for (int p = 0; p < 4; p++) {
            int r = r0 + p * 16;
            *(float4*)&tile[r][c] = *(const float4*)(W + (size_t)(k0 + r) * 512 + j0 + c);
        }
        __syncthreads();
        int kc = (tid & 15) * 4, jr0 = tid >> 4;
#pragma unroll
        for (int p = 0; p < 4; p++) {
            int jr = jr0 + p * 16;
            float v0 = tile[kc + 0][jr], v1 = tile[kc + 1][jr];
            float v2 = tile[kc + 2][jr], v3 = tile[kc + 3][jr];
            if (which == 0) {
                v0 *= g[k0 + kc + 0]; v1 *= g[k0 + kc + 1];
                v2 *= g[k0 + kc + 2]; v3 *= g[k0 + kc + 3];
            }
            u16x4 ob = {f2bf(v0), f2bf(v1), f2bf(v2), f2bf(v3)};
            *(u16x4*)(Tb + (size_t)(j0 + jr) * 512 + k0 + kc) = ob;
        }
        if (which == 0) {                      // u/cb partials over this k-block
            int jl = tid & 63, qt = tid >> 6;
            float su = 0.f, sc = 0.f;
#pragma unroll
            for (int r = 0; r < 16; r++) {
                int kk = qt * 16 + r;
                float w = tile[kk][jl];
                su += g[k0 + kk] * w; sc += b[k0 + kk] * w;
            }
            __syncthreads();
            float* red = &tile[0][0];
            red[qt * 128 + jl] = su;
            red[qt * 128 + 64 + jl] = sc;
            __syncthreads();
            if (tid < 64) {
                float s = red[tid] + red[128 + tid] + red[256 + tid] + red[384 + tid];
                ws[WS_UP + (size_t)(k0 >> 6) * 512 + j0 + tid] = s;
            } else if (tid < 128) {
                int j = tid - 64;
                float s = red[64 + j] + red[192 + j] + red[320 + j] + red[448 + j];
                ws[WS_CBP + (size_t)(k0 >> 6) * 512 + j0 + j] = s;
            }
        }
    }
}

// ------- K1 (proj, q/k/v fused): round-12/13/14 proven structure -----------
template <int CPX>
__global__ __launch_bounds__(512, 2) void k_proj(
    const u16* __restrict__ A, const u16* __restrict__ B, float* __restrict__ ws) {
    __shared__ char smem[131072];              // 4 bufs x {Aq,Ak,Av,B}x8KB
    int tid = threadIdx.x;
    int wid = tid >> 6, lane = tid & 63;
    int i15 = lane & 15, q4 = lane >> 4;
    int wm = wid >> 2, wn = wid & 3;
    int flat = blockIdx.x + (blockIdx.y << 2);
    int swz = (flat & 7) * CPX + (flat >> 3);
    int c0 = (swz & 3) * 128, m0 = (swz >> 2) * 128;   // m0 in 0..8064

    floatx4 acc[3][4][2];
#pragma unroll
    for (int t = 0; t < 3; t++)
#pragma unroll
        for (int i = 0; i < 4; i++)
#pragma unroll
            for (int j = 0; j < 2; j++) acc[t][i][j] = (floatx4){0.f, 0.f, 0.f, 0.f};

    const u16* gB = B + (size_t)c0 * 512;

    auto stage = [&](int ks, int buf) {
        int o = wid * 1024 + lane * 16;        // byte off in 8KB region
        int srow = o >> 6, s = (o >> 4) & 3;
        int cch = (s - (srow >> 1)) & 3;       // inverse rotation
        size_t roff = (size_t)srow * 512 + ks * 32 + cch * 8;
        char* base = smem + buf * 32768 + wid * 1024;
#pragma unroll
        for (int t = 0; t < 3; t++) {
            const u16* ga = A + (size_t)(t * 8192 + m0) * 512 + roff;
            __builtin_amdgcn_global_load_lds(
                (const __attribute__((address_space(1))) void*)ga,
                (__attribute__((address_space(3))) void*)(base + t * 8192), 16, 0, 0);
        }
        __builtin_amdgcn_global_load_lds(
            (const __attribute__((address_space(1))) void*)(gB + roff),
            (__attribute__((address_space(3))) void*)(base + 24576), 16, 0, 0);
    };

    stage(0, 0);
    stage(1, 1);
    stage(2, 2);
    __builtin_amdgcn_sched_barrier(0);
#pragma unroll
    for (int ks = 0; ks < 16; ks++) {
        __builtin_amdgcn_sched_barrier(0);
        if (ks <= 13)      asm volatile("s_waitcnt vmcnt(8)" ::: "memory");
        else if (ks == 14) asm volatile("s_waitcnt vmcnt(4)" ::: "memory");
        else               asm volatile("s_waitcnt vmcnt(0)" ::: "memory");
        __builtin_amdgcn_s_barrier();
        __builtin_amdgcn_sched_barrier(0);
        if (ks + 3 < 16) stage(ks + 3, (ks + 3) & 3);   // post-barrier: safe
        __builtin_amdgcn_sched_barrier(0);
        char* bb = smem + (ks & 3) * 32768;
        short8 b[2];
#pragma unroll
        for (int f = 0; f < 2; f++) {
            int rb = wn * 32 + f * 16 + i15;
            int sb = (q4 + (rb >> 1)) & 3;     // rotation swizzle
            b[f] = *(const short8*)(bb + 24576 + rb * 64 + sb * 16);
        }
#pragma unroll
        for (int t = 0; t < 3; t++) {
            short8 a[4];
#pragma unroll
            for (int f = 0; f < 4; f++) {
                int ra = wm * 64 + f * 16 + i15;
                int sa = (q4 + (ra >> 1)) & 3;
                a[f] = *(const short8*)(bb + t * 8192 + ra * 64 + sa * 16);
            }
#pragma unroll
            for (int fm = 0; fm < 4; fm++)
#pragma unroll
                for (int fn = 0; fn < 2; fn++)
                    acc[t][fm][fn] = __builtin_amdgcn_mfma_f32_16x16x32_bf16(
                        a[fm], b[fn], acc[t][fm][fn], 0, 0, 0);
        }
    }

    // ---------------- epilogue: per-t LN fold + stats + writes ----------
    float2* rowred = (float2*)smem;            // [8 waves][64 rows]
    float2* colred = (float2*)(smem + 4096);   // [8 waves][32 cols]
    float2* lnfin  = (float2*)(smem + 6144);   // [2 hp][128 rows] (inv,mean)
    int nbase = m0 & 1023;                     // per-hq row base
    int qg = m0 >> 10, nblk = (m0 >> 7) & 7;
    int hp = wn >> 1;
    int h = (c0 >> 6) + hp, hq = h * 8 + qg;
    int dwn = (wn & 1) * 32;
    float u_[2], cb_[2];
#pragma unroll
    for (int fn = 0; fn < 2; fn++) {
        int gc = c0 + wn * 32 + fn * 16 + i15;
        float su = 0.f, sc = 0.f;
#pragma unroll
        for (int p = 0; p < 8; p++) {
            su += ws[WS_UP + (size_t)p * 512 + gc];
            sc += ws[WS_CBP + (size_t)p * 512 + gc];
        }
        u_[fn] = su; cb_[fn] = sc;
    }
#pragma unroll
    for (int t = 0; t < 3; t++) {
        __syncthreads();                       // scratch free (K-loop / prev t)
        float csum[2] = {0, 0}, css[2] = {0, 0};
#pragma unroll
        for (int fm = 0; fm < 4; fm++) {
#pragma unroll
            for (int reg = 0; reg < 4; reg++) {
                int grow = t * 8192 + m0 + wm * 64 + fm * 16 + q4 * 4 + reg;  // LNST row
                float2 st = *(const float2*)(ws + WS_LNST + (size_t)grow * 2);
                float mu = st.x, rs = st.y;
                float r1 = 0.f, r2 = 0.f;
#pragma unroll
                for (int fn = 0; fn < 2; fn++) {
                    float val = rs * acc[t][fm][fn][reg] - rs * mu * u_[fn] + cb_[fn];
                    acc[t][fm][fn][reg] = val;
                    r1 += val; r2 += val * val;
                    csum[fn] += val; css[fn] += val * val;
                }
                if (t < 2) {
#pragma unroll
                    for (int m = 1; m < 16; m <<= 1) {
                        r1 += __shfl_xor(r1, m, 64);
                        r2 += __shfl_xor(r2, m, 64);
                    }
                    if (i15 == fm * 4 + reg)
                        rowred[(size_t)wid * 64 + fm * 16 + q4 * 4 + reg] = (float2){r1, r2};
                }
            }
        }
        if (t < 2) {
#pragma unroll
            for (int fn = 0; fn < 2; fn++) {
                float s1 = csum[fn], s2 = css[fn];
                s1 += __shfl_xor(s1, 16, 64); s1 += __shfl_xor(s1, 32, 64);
                s2 += __shfl_xor(s2, 16, 64); s2 += __shfl_xor(s2, 32, 64);
                if (q4 == fn) colred[(size_t)wid * 32 + fn * 16 + i15] = (float2){s1, s2};
            }
        }
        __syncthreads();
        if (t < 2) {
            float* invn = ws + (t ? WS_INVNK : WS_INVNQ);
            float* mean = ws + (t ? WS_KMEAN : WS_QMEAN);
            if (tid < 256) {                   // 2 wm x 2 headpair x 64 rows
                int wmf = tid >> 7, p = (tid >> 6) & 1, r = tid & 63;
                float2 aa = rowred[(size_t)(wmf * 4 + 2 * p) * 64 + r];
                float2 bb2 = rowred[(size_t)(wmf * 4 + 2 * p + 1) * 64 + r];
                float s1 = aa.x + bb2.x, s2 = aa.y + bb2.y;
                float iv = rsqrtf(s2), mn = s1 * (1.f / 64.f);
                int n = nbase + wmf * 64 + r;
                int hhq = ((c0 >> 6) + p) * 8 + qg;
                invn[(size_t)hhq * 1024 + n] = iv;
                mean[(size_t)hhq * 1024 + n] = mn;
                lnfin[p * 128 + wmf * 64 + r] = (float2){iv, mn};
            } else if (tid < 384) {            // 2 headpair x 64 cols
                int tt = tid - 256;
                int p = tt >> 6, d = tt & 63;
                int wnn = 2 * p + (d >> 5), loc = d & 31;
                float2 aa = colred[(size_t)(0 * 4 + wnn) * 32 + loc];
                float2 bb2 = colred[(size_t)(1 * 4 + wnn) * 32 + loc];
                int hhq = ((c0 >> 6) + p) * 8 + qg;
                *(float2*)(ws + WS_COLP +
                           (size_t)(((t * 64 + hhq) * 8 + nblk) * 64 + d) * 2) =
                    (float2){aa.x + bb2.x, aa.y + bb2.y};
            }
        }
        __syncthreads();
        if (t == 0) {                          // FQ row-major [hq][n][64]
            u16* fout = (u16*)(ws + WS_FQ) + (size_t)hq * 65536;
#pragma unroll
            for (int fm = 0; fm < 4; fm++)
#pragma unroll
                for (int reg = 0; reg < 4; reg++) {
                    int n = nbase + wm * 64 + fm * 16 + q4 * 4 + reg;
#pragma unroll
                    for (int fn = 0; fn < 2; fn++)
                        fout[(size_t)n * 64 + dwn + fn * 16 + i15] =
                            f2bf(acc[0][fm][fn][reg]);
                }
        } else if (t == 1) {                   // FKTs/FKTc Gram frag
            u16* fs = (u16*)(ws + WS_FKTS) + (size_t)hq * 65536;
            u16* fc = (u16*)(ws + WS_FKTC) + (size_t)hq * 65536;
#pragma unroll
            for (int fn = 0; fn < 2; fn++) {
                int eoff = ((wn & 1) * 2 + fn) * 16384 + i15 * 32;
#pragma unroll
                for (int fm = 0; fm < 4; fm++) {
                    int n0l = wm * 64 + fm * 16 + q4 * 4;
                    int n0 = nbase + n0l;
                    int off = eoff + (n0 >> 5) * 512 + ((n0 >> 3) & 3) * 8 + (n0 & 7);
                    u16x4 vs, vc;
#pragma unroll
                    for (int reg = 0; reg < 4; reg++) {
                        float2 im = lnfin[hp * 128 + n0l + reg];
                        float val = acc[1][fm][fn][reg];
                        vs[reg] = f2bf(val * im.x);
                        vc[reg] = f2bf(val - im.y);
                    }
                    *(u16x4*)(fs + off) = vs;
                    *(u16x4*)(fc + off) = vc;
                }
            }
        } else {                               // FVT Gram frag
            u16* fv = (u16*)(ws + WS_FVT) + (size_t)hq * 65536;
#pragma unroll
            for (int fn = 0; fn < 2; fn++) {
                int doff = ((wn & 1) * 2 + fn) * 16384 + i15 * 32;
#pragma unroll
                for (int fm = 0; fm < 4; fm++) {
                    int n0 = nbase + wm * 64 + fm * 16 + q4 * 4;
                    int off = doff + (n0 >> 5) * 512 + ((n0 >> 3) & 3) * 8 + (n0 & 7);
                    u16x4 v4;
#pragma unroll
                    for (int reg = 0; reg < 4; reg++) v4[reg] = f2bf(acc[2][fm][fn][reg]);
                    *(u16x4*)(fv + off) = v4;
                }
            }
        }
    }
}

// ---------------- K3a: parallel COLP reduction -> GSUM[2][8][64][2] --------
__global__ __launch_bounds__(256) void k_gatered(float* __restrict__ ws) {
    int h = blockIdx.x, t = blockIdx.y;
    int tid = threadIdx.x;
    int c = tid & 127, rg = tid >> 7;
    const float* base = ws + WS_COLP + ((size_t)(t * 64 + h * 8) * 8) * 128;
    float s = 0.f;
#pragma unroll 8
    for (int r = rg * 32; r < rg * 32 + 32; r++) s += base[(size_t)r * 128 + c];
    __shared__ float red[2][128];
    red[rg][c] = s;
    __syncthreads();
    if (tid < 128)
        ws[WS_GSUM + ((size_t)t * 8 + h) * 128 + tid] = red[0][tid] + red[1][tid];
}

// ------- K4 (MFMA): M,C Gram matrices per hq, K=1024, barrier-free ---------
// + gate MLP folded in: blocks with hq&7==0 compute WGATE[hq>>3] (wave 0),
//   reading GSUM directly from global (same arithmetic order as old k_gate).
__global__ __launch_bounds__(256) void k_mc(
    const float* __restrict__ pw1, const float* __restrict__ pb1,
    const float* __restrict__ plg, const float* __restrict__ plb,
    const float* __restrict__ pw2, const float* __restrict__ pb2,
    float* __restrict__ ws) {
    int hq = blockIdx.x;
    int tid = threadIdx.x, wid = tid >> 6, lane = tid & 63;
    int i15 = lane & 15, q4 = lane >> 4;
    int we = wid >> 1, wd = wid & 1;
    const u16* fs = (const u16*)(ws + WS_FKTS) + (size_t)hq * 65536;
    const u16* fc = (const u16*)(ws + WS_FKTC) + (size_t)hq * 65536;
    const u16* fv = (const u16*)(ws + WS_FVT) + (size_t)hq * 65536;
    floatx4 aM[2][2], aC[2][2];
#pragma unroll
    for (int f = 0; f < 2; f++)
#pragma unroll
        for (int g = 0; g < 2; g++) {
            aM[f][g] = (floatx4){0.f, 0.f, 0.f, 0.f};
            aC[f][g] = (floatx4){0.f, 0.f, 0.f, 0.f};
        }
#pragma unroll 8
    for (int ks = 0; ks < 32; ks++) {
        short8 as_[2], ac_[2], b_[2];
#pragma unroll
        for (int f = 0; f < 2; f++) {
            int off = (we * 2 + f) * 16384 + ks * 512 + i15 * 32 + q4 * 8;
            as_[f] = *(const short8*)(fs + off);
            ac_[f] = *(const short8*)(fc + off);
        }
#pragma unroll
        for (int g = 0; g < 2; g++)
            b_[g] = *(const short8*)(fv + (wd * 2 + g) * 16384 + ks * 512 +
                                     i15 * 32 + q4 * 8);
#pragma unroll
        for (int f = 0; f < 2; f++)
#pragma unroll
            for (int g = 0; g < 2; g++) {
                aM[f][g] = __builtin_amdgcn_mfma_f32_16x16x32_bf16(
                    as_[f], b_[g], aM[f][g], 0, 0, 0);
                aC[f][g] = __builtin_amdgcn_mfma_f32_16x16x32_bf16(
                    ac_[f], b_[g], aC[f][g], 0, 0, 0);
            }
    }
    __shared__ float tile[2][64][65];
    __shared__ float cred[4][64];
#pragma unroll
    for (int f = 0; f < 2; f++)
#pragma unroll
        for (int g = 0; g < 2; g++)
#pragma unroll
            for (int reg = 0; reg < 4; reg++) {
                int e = we * 32 + f * 16 + q4 * 4 + reg;
                int d = wd * 32 + g * 16 + i15;
                tile[0][e][d] = aM[f][g][reg];
                tile[1][e][d] = aC[f][g][reg];
            }
    __syncthreads();
    int d = tid & 63, ec = tid >> 6;
    float cp = 0.f;
#pragma unroll
    for (int i = 0; i < 16; i++) cp += tile[1][ec * 16 + i][d];
    cred[ec][d] = cp;
#pragma unroll
    for (int mat = 0; mat < 2; mat++) {
        u16x8 p0, p1;
#pragma unroll
        for (int i = 0; i < 8; i++) {
            p0[i] = f2bf(tile[mat][ec * 16 + i][d]);
            p1[i] = f2bf(tile[mat][ec * 16 + 8 + i][d]);
        }
        u16* dst = (u16*)(ws + (mat ? WS_CTB : WS_MTB)) + (size_t)hq * 4096 + d * 64 + ec * 16;
        *(u16x8*)dst = p0;
        *(u16x8*)(dst + 8) = p1;
    }
    __syncthreads();
    if (tid < 64)
        ws[WS_COLC + (size_t)hq * 64 + tid] =
            cred[0][tid] + cred[1][tid] + cred[2][tid] + cred[3][tid];

    // ---- folded gate MLP (exactly old k_gate arithmetic, wave 0 only) ----
    if ((hq & 7) == 0 && wid == 0) {
        float Sq = 0, SSq = 0, Sk = 0, SSk = 0;
#pragma unroll
        for (int h8 = 0; h8 < 8; h8++) {
            Sq  += ws[WS_GSUM + (size_t)(0 * 8 + h8) * 128 + lane * 2];
            SSq += ws[WS_GSUM + (size_t)(0 * 8 + h8) * 128 + lane * 2 + 1];
            Sk  += ws[WS_GSUM + (size_t)(1 * 8 + h8) * 128 + lane * 2];
            SSk += ws[WS_GSUM + (size_t)(1 * 8 + h8) * 128 + lane * 2 + 1];
        }
        const float NR = 65536.f;
        float stdq = sqrtf((SSq - Sq * Sq / NR) / (NR - 1.f) + 1e-4f);
        float stdk = sqrtf((SSk - Sk * Sk / NR) / (NR - 1.f) + 1e-4f);
        float vpen = (wsum(fmaxf(1.f - stdq, 0.f)) + wsum(fmaxf(1.f - stdk, 0.f))) * (1.f / 64.f);
        int h = hq >> 3;
        float y = pb1[lane];
#pragma unroll 8
        for (int i = 0; i < 64; i++) {
            y = fmaf(ws[WS_GSUM + (size_t)(0 * 8 + h) * 128 + i * 2] * (1.f / 8192.f),
                     pw1[i * 64 + lane], y);
            y = fmaf(ws[WS_GSUM + (size_t)(1 * 8 + h) * 128 + i * 2] * (1.f / 8192.f),
                     pw1[(64 + i) * 64 + lane], y);
        }
        float mu = wsum(y) * (1.f / 64.f);
        float dv = y - mu;
        float var = wsum(dv * dv) * (1.f / 64.f);
        float z = dv * rsqrtf(var + 1e-5f) * plg[lane] + plb[lane];
        float r = fmaxf(z, 0.f);
        float sdot = wsum(r * pw2[lane]);
        if (lane == 0) {
            float wv = 1.f / (1.f + expf(-(sdot + pb2[0])));
            ws[WS_WGATE + h] = wv / (1.f + vpen);
        }
    }
}

// ---- K5 (MFMA): out_attn = c1*inv*(fq@M) + c2*(fq@C - qm*colC)  bf16 out ---
__global__ __launch_bounds__(256) void k_apply(float* __restrict__ ws) {
    int nt = blockIdx.x, hq = blockIdx.y;
    int h = hq >> 3, qg = hq & 7;
    __shared__ u16 mt[2][4096];                // swizzled M^T, C^T (8KB each)
    __shared__ float invqm[256][2];
    __shared__ u16 outs[256][66];              // +2 pad
    int tid = threadIdx.x, wid = tid >> 6, lane = tid & 63;
    int i15 = lane & 15, q4 = lane >> 4;
#pragma unroll
    for (int mat = 0; mat < 2; mat++) {
        const u16* src = (const u16*)(ws + (mat ? WS_CTB : WS_MTB)) + (size_t)hq * 4096;
#pragma unroll
        for (int it = 0; it < 2; it++) {
            int i = tid + it * 256;            // 16B chunk id, 512 total
            int d = i >> 3, c8 = i & 7;
            u16x8 v = *(const u16x8*)(src + i * 8);
            int byte = d * 128 + ((c8 * 16) ^ ((d & 7) << 4));
            *(u16x8*)((char*)&mt[mat][0] + byte) = v;
        }
    }
    int R0 = nt * 256;
    invqm[tid][0] = ws[WS_INVNQ + (size_t)hq * 1024 + R0 + tid];
    invqm[tid][1] = ws[WS_QMEAN + (size_t)hq * 1024 + R0 + tid];
    float wv = ws[WS_WGATE + h];
    float c1 = 1.f - wv, c2 = wv * (1.f / 64.f);
    float colc[4];
#pragma unroll
    for (int fn = 0; fn < 4; fn++)
        colc[fn] = ws[WS_COLC + (size_t)hq * 64 + fn * 16 + i15];
    __syncthreads();
    const u16* fq = (const u16*)(ws + WS_FQ) + (size_t)hq * 65536 +
                    (size_t)(R0 + wid * 64) * 64;
    floatx4 aM[4][4], aC[4][4];
#pragma unroll
    for (int i = 0; i < 4; i++)
#pragma unroll
        for (int j = 0; j < 4; j++) {
            aM[i][j] = (floatx4){0.f, 0.f, 0.f, 0.f};
            aC[i][j] = (floatx4){0.f, 0.f, 0.f, 0.f};
        }
#pragma unroll
    for (int ks = 0; ks < 2; ks++) {
        short8 a[4], bM[4], bC[4];
#pragma unroll
        for (int f = 0; f < 4; f++)
            a[f] = *(const short8*)(fq + (size_t)(f * 16 + i15) * 64 + q4 * 8 + ks * 32);
#pragma unroll
        for (int f = 0; f < 4; f++) {
            int col = f * 16 + i15;
            int byte = col * 128 + ((q4 * 16 + ks * 64) ^ ((col & 7) << 4));
            bM[f] = *(const short8*)((char*)&mt[0][0] + byte);
            bC[f] = *(const short8*)((char*)&mt[1][0] + byte);
        }
#pragma unroll
        for (int fm = 0; fm < 4; fm++)
#pragma unroll
            for (int fn = 0; fn < 4; fn++) {
                aM[fm][fn] = __builtin_amdgcn_mfma_f32_16x16x32_bf16(
                    a[fm], bM[fn], aM[fm][fn], 0, 0, 0);
                aC[fm][fn] = __builtin_amdgcn_mfma_f32_16x16x32_bf16(
                    a[fm], bC[fn], aC[fm][fn], 0, 0, 0);
            }
    }
#pragma unroll
    for (int fm = 0; fm < 4; fm++)
#pragma unroll
        for (int reg = 0; reg < 4; reg++) {
            int rloc = wid * 64 + fm * 16 + q4 * 4 + reg;
            float iv = invqm[rloc][0], qmv = invqm[rloc][1];
#pragma unroll
            for (int fn = 0; fn < 4; fn++) {
                float val = c1 * iv * aM[fm][fn][reg] +
                            c2 * (aC[fm][fn][reg] - qmv * colc[fn]);
                outs[rloc][fn * 16 + i15] = f2bf(val);
            }
        }
    __syncthreads();
    u16* oat = (u16*)(ws + WS_OATT);
#pragma unroll
    for (int it = 0; it < 8; it++) {
        int c = tid + it * 256;                // 16B chunk id, 2048 total
        int row = c >> 3, c8 = (c & 7) * 8;
        u16x8 v = *(const u16x8*)&outs[row][c8];
        *(u16x8*)(oat + ((size_t)qg * 1024 + R0 + row) * 512 + h * 64 + c8) = v;
    }
}

// ---------------- K6 (out-proj GEMM): round-10 proven structure ------------
template <int CPX>
__global__ __launch_bounds__(512, 4) void k_gemm_out(
    const u16* __restrict__ A, const u16* __restrict__ B,
    float* __restrict__ out, const float* __restrict__ bias) {
    __shared__ char smem[65536];               // 4 bufs x (A 8K + B 8K)
    int tid = threadIdx.x;
    int wid = tid >> 6, lane = tid & 63;
    int i15 = lane & 15, q4 = lane >> 4;
    int wm = wid >> 2, wn = wid & 3;
    int flat = blockIdx.x + (blockIdx.y << 2);
    int swz = (flat & 7) * CPX + (flat >> 3);
    int c0 = (swz & 3) * 128, m0 = (swz >> 2) * 128;

    floatx4 acc[4][2];
#pragma unroll
    for (int i = 0; i < 4; i++)
#pragma unroll
        for (int j = 0; j < 2; j++) acc[i][j] = (floatx4){0.f, 0.f, 0.f, 0.f};

    const u16* gA = A + (size_t)m0 * 512;
    const u16* gB = B + (size_t)c0 * 512;

    auto stage = [&](int ks, int buf) {
        int o = wid * 1024 + lane * 16;
        int srow = o >> 6, s = (o >> 4) & 3;
        int cch = (s - (srow >> 1)) & 3;
        const u16* ga = gA + (size_t)srow * 512 + ks * 32 + cch * 8;
        const u16* gb = gB + (size_t)srow * 512 + ks * 32 + cch * 8;
        char* la = smem + buf * 16384 + wid * 1024;
        char* lb = smem + buf * 16384 + 8192 + wid * 1024;
        __builtin_amdgcn_global_load_lds(
            (const __attribute__((address_space(1))) void*)ga,
            (__attribute__((address_space(3))) void*)la, 16, 0, 0);
        __builtin_amdgcn_global_load_lds(
            (const __attribute__((address_space(1))) void*)gb,
            (__attribute__((address_space(3))) void*)lb, 16, 0, 0);
    };

    stage(0, 0);
    stage(1, 1);
    stage(2, 2);
    __builtin_amdgcn_sched_barrier(0);
#pragma unroll
    for (int ks = 0; ks < 16; ks++) {
        __builtin_amdgcn_sched_barrier(0);
        if (ks <= 13)      asm volatile("s_waitcnt vmcnt(4)" ::: "memory");
        else if (ks == 14) asm volatile("s_waitcnt vmcnt(2)" ::: "memory");
        else               asm volatile("s_waitcnt vmcnt(0)" ::: "memory");
        __builtin_amdgcn_s_barrier();
        __builtin_amdgcn_sched_barrier(0);
        if (ks + 3 < 16) stage(ks + 3, (ks + 3) & 3);
        __builtin_amdgcn_sched_barrier(0);
        int buf = ks & 3;
        short8 a[4], b[2];
#pragma unroll
        for (int f = 0; f < 4; f++) {
            int ra = wm * 64 + f * 16 + i15;
            int sa = (q4 + (ra >> 1)) & 3;
            a[f] = *(const short8*)(smem + buf * 16384 + ra * 64 + sa * 16);
        }
#pragma unroll
        for (int f = 0; f < 2; f++) {
            int rb = wn * 32 + f * 16 + i15;
            int sb = (q4 + (rb >> 1)) & 3;
            b[f] = *(const short8*)(smem + buf * 16384 + 8192 + rb * 64 + sb * 16);
        }
#pragma unroll
        for (int fm = 0; fm < 4; fm++)
#pragma unroll
            for (int fn = 0; fn < 2; fn++)
                acc[fm][fn] = __builtin_amdgcn_mfma_f32_16x16x32_bf16(
                    a[fm], b[fn], acc[fm][fn], 0, 0, 0);
    }
#pragma unroll
    for (int fm = 0; fm < 4; fm++)
#pragma unroll
        for (int reg = 0; reg < 4; reg++) {
            int gm = m0 + wm * 64 + fm * 16 + q4 * 4 + reg;
#pragma unroll
            for (int fn = 0; fn < 2; fn++) {
                int gc = c0 + wn * 32 + fn * 16 + i15;
                out[(size_t)gm * 512 + gc] = acc[fm][fn][reg] + bias[gc];
            }
        }
}

// ---------------- host launch ----------------
extern "C" void kernel_launch(void* const* d_in, const int* in_sizes, int n_in,
                              void* d_out, int out_size, void* d_ws, size_t ws_size,
                              hipStream_t stream) {
    (void)in_sizes; (void)n_in; (void)out_size; (void)ws_size;
    const float* q = (const float*)d_in[0];
    const float* k = (const float*)d_in[1];
    const float* v = (const float*)d_in[2];
    const float* ln_g = (const float*)d_in[3];
    const float* ln_b = (const float*)d_in[4];
    const float* w_in = (const float*)d_in[5];
    const float* p_w1 = (const float*)d_in[6];
    const float* p_b1 = (const float*)d_in[7];
    const float* p_ln_g = (const float*)d_in[8];
    const float* p_ln_b = (const float*)d_in[9];
    const float* p_w2 = (const float*)d_in[10];
    const float* p_b2 = (const float*)d_in[11];
    const float* w_out = (const float*)d_in[12];
    const float* b_out = (const float*)d_in[13];
    float* ws = (float*)d_ws;
    float* out = (float*)d_out;

    k_head<<<6272, 256, 0, stream>>>(q, k, v, w_in, w_out, ln_g, ln_b, ws);
    k_proj<32><<<dim3(4, 64), 512, 0, stream>>>((const u16*)(ws + WS_XBF),
                                                (const u16*)(ws + WS_WPT), ws);
    k_gatered<<<dim3(8, 2), 256, 0, stream>>>(ws);
    k_mc<<<64, 256, 0, stream>>>(p_w1, p_b1, p_ln_g, p_ln_b, p_w2, p_b2, ws);
    k_apply<<<dim3(4, 64), 256, 0, stream>>>(ws);
    k_gemm_out<32><<<dim3(4, 64), 512, 0, stream>>>((const u16*)(ws + WS_OATT),
                                                    (const u16*)(ws + WS_WOT), out, b_out);
}